// Round 5
// baseline (744.116 us; speedup 1.0000x reference)
//
#include <hip/hip_runtime.h>
#include <hip/hip_bf16.h>

// Problem constants
#define BB 64
#define SS 512
#define DD 128
#define NROW (BB * SS)          // 32768
#define SZ ((size_t)NROW * DD)  // 4,194,304 elems per [B,S,128] slice

#define LOG2E 1.4426950408889634f
#define QSCALE (0.125f * LOG2E)

typedef __attribute__((ext_vector_type(8))) short short8;
typedef __attribute__((ext_vector_type(4))) float f32x4;
typedef __attribute__((ext_vector_type(2))) unsigned int uint2v;

// WB (converted-weight buffer) element offsets, all bf16:
#define WB_P1 0          // fc1W^T [128][320] (K=300 pad 320)
#define WB_P2 40960      // fc2W^T [128][64]  (K=35 pad 64)
#define WB_P3 49152      // fc3W^T [128][96]  (K=74 pad 96)
#define WB_QKVD 61440    // [4 op][6 u][128 n][128 k]  (op0=Wq prescaled by QSCALE)
#define WB_WIH 454656    // [6 rec][384 n][128 k]  (prescaled by log2e/2log2e)
#define WB_WHH 749568    // [6 rec][384 n][128 k]  (prescaled by log2e/2log2e)
#define WB_TOTAL 1044480

__device__ __forceinline__ float frcp_(float x) { return __builtin_amdgcn_rcpf(x); }
__device__ __forceinline__ float fexp2_(float x) { return __builtin_amdgcn_exp2f(x); }
__device__ __forceinline__ float b2f(unsigned short u) {
  union { unsigned int i; float f; } x; x.i = ((unsigned int)u) << 16; return x.f;
}
__device__ __forceinline__ unsigned short f2b(float f) {
  __hip_bfloat16 b = __float2bfloat16(f);
  return *reinterpret_cast<unsigned short*>(&b);
}
__device__ __forceinline__ unsigned short f2b_trunc(float f) {
  union { float f; unsigned int i; } x; x.f = f; return (unsigned short)(x.i >> 16);
}
// pack 2 f32 -> u32 of 2 bf16 (lo=src0, hi=src1), RNE — single HW instr.
__device__ __forceinline__ unsigned int cvtpk(float lo, float hi) {
  unsigned int r;
  asm("v_cvt_pk_bf16_f32 %0, %1, %2" : "=v"(r) : "v"(lo), "v"(hi));
  return r;
}

// ---------------------------------------------------------------------------
// Weight prep.  Wq prescaled by QSCALE; GRU weights prescaled by log2e (r,z)
// / 2log2e (n).  gbihs = scale*(gbih + gbhh) for r,z gates; for n gate
// gbihs = scale*gbih only (bhh_n carried by gru kernel's cbhn accumulator).
// ---------------------------------------------------------------------------
__global__ __launch_bounds__(256) void prep_kernel(
    const float* __restrict__ fc1W, const float* __restrict__ fc2W,
    const float* __restrict__ fc3W, const float* __restrict__ Wq,
    const float* __restrict__ Wk, const float* __restrict__ Wv,
    const float* __restrict__ Wd, const float* __restrict__ gWih,
    const float* __restrict__ gWhh, const float* __restrict__ gbih,
    const float* __restrict__ gbhh, const float* __restrict__ bq,
    unsigned short* __restrict__ WB, float* __restrict__ gbihs,
    float* __restrict__ bqs) {
  for (int idx = blockIdx.x * 256 + threadIdx.x; idx < WB_TOTAL;
       idx += gridDim.x * 256) {
    float v;
    if (idx < WB_P2) {
      int n = idx / 320, k = idx % 320;
      v = (k < 300) ? fc1W[k * 128 + n] : 0.f;
    } else if (idx < WB_P3) {
      int r = idx - WB_P2; int n = r >> 6, k = r & 63;
      v = (k < 35) ? fc2W[k * 128 + n] : 0.f;
    } else if (idx < WB_QKVD) {
      int r = idx - WB_P3; int n = r / 96, k = r % 96;
      v = (k < 74) ? fc3W[k * 128 + n] : 0.f;
    } else if (idx < WB_WIH) {
      int r = idx - WB_QKVD;
      int op = r / 98304; int r2 = r % 98304;
      int u = r2 >> 14; int r3 = r2 & 16383;
      int n = r3 >> 7, k = r3 & 127;
      const float* src = (op == 0) ? Wq : (op == 1) ? Wk : (op == 2) ? Wv : Wd;
      v = src[u * 16384 + k * 128 + n];
      if (op == 0) v *= QSCALE;
    } else if (idx < WB_WHH) {
      int r = idx - WB_WIH;
      int r3 = r % 49152;  // within rec: [384 n][128 k]
      int gate = (r3 >> 7) >> 7;
      v = gWih[r] * (gate < 2 ? LOG2E : 2.f * LOG2E);
    } else {
      int r = idx - WB_WHH;
      int r3 = r % 49152;
      int gate = (r3 >> 7) >> 7;
      v = gWhh[r] * (gate < 2 ? LOG2E : 2.f * LOG2E);
    }
    WB[idx] = f2b(v);
  }
  for (int idx = blockIdx.x * 256 + threadIdx.x; idx < 6 * 384;
       idx += gridDim.x * 256) {
    int gate = (idx % 384) >> 7;
    float v = gbih[idx] + (gate < 2 ? gbhh[idx] : 0.f);
    gbihs[idx] = v * (gate < 2 ? LOG2E : 2.f * LOG2E);
  }
  for (int idx = blockIdx.x * 256 + threadIdx.x; idx < 6 * 128;
       idx += gridDim.x * 256) {
    bqs[idx] = bq[idx] * QSCALE;
  }
}

// ---------------------------------------------------------------------------
// GArg: shared by both gemm kernels.
// ---------------------------------------------------------------------------
struct GArg {
  const void* A; const unsigned short* W; const float* bias; void* C;
  int Ka, Kp, abf, cbf, cs; float* vsum;
};
struct GArgs { GArg g[18]; };

// ---------------------------------------------------------------------------
// gemm_b: loop/LDS path, used ONLY for the f32-input projections (Kp<=320).
// ---------------------------------------------------------------------------
__global__ __launch_bounds__(256) void gemm_b(GArgs args) {
  const GArg ga = args.g[blockIdx.z];
  const int ny = blockIdx.y;
  __shared__ unsigned short As[128 * 40];
  __shared__ unsigned short Ws[128 * 40];
  const int t = threadIdx.x;
  const int w = t >> 6, lane = t & 63, q = lane >> 4, lm = lane & 15;
  const int wm = w >> 1, wn = w & 1;
  const int m0 = blockIdx.x * 128;
  const int row = t >> 1, cb = (t & 1) * 16;
  f32x4 acc[4][4];
#pragma unroll
  for (int i = 0; i < 4; ++i)
#pragma unroll
    for (int j = 0; j < 4; ++j) acc[i][j] = (f32x4){0.f, 0.f, 0.f, 0.f};

  for (int kt = 0; kt < ga.Kp; kt += 32) {
    {
      const float* Ag = (const float*)ga.A + (size_t)(m0 + row) * ga.Ka + kt + cb;
      unsigned short tmp[16];
#pragma unroll
      for (int j = 0; j < 16; ++j) {
        int k = kt + cb + j;
        tmp[j] = (k < ga.Ka) ? f2b(Ag[j]) : 0;
      }
      *reinterpret_cast<short8*>(&As[row * 40 + cb]) =
          *reinterpret_cast<short8*>(&tmp[0]);
      *reinterpret_cast<short8*>(&As[row * 40 + cb + 8]) =
          *reinterpret_cast<short8*>(&tmp[8]);
    }
    {
      const unsigned short* Wg =
          ga.W + (size_t)(ny * 128 + row) * ga.Kp + kt + cb;
      short8 v0 = *reinterpret_cast<const short8*>(Wg);
      short8 v1 = *reinterpret_cast<const short8*>(Wg + 8);
      *reinterpret_cast<short8*>(&Ws[row * 40 + cb]) = v0;
      *reinterpret_cast<short8*>(&Ws[row * 40 + cb + 8]) = v1;
    }
    __syncthreads();
    short8 af[4], bfv[4];
#pragma unroll
    for (int mi = 0; mi < 4; ++mi)
      af[mi] = *reinterpret_cast<const short8*>(
          &As[(wm * 64 + mi * 16 + lm) * 40 + q * 8]);
#pragma unroll
    for (int ni = 0; ni < 4; ++ni)
      bfv[ni] = *reinterpret_cast<const short8*>(
          &Ws[(wn * 64 + ni * 16 + lm) * 40 + q * 8]);
#pragma unroll
    for (int mi = 0; mi < 4; ++mi)
#pragma unroll
      for (int ni = 0; ni < 4; ++ni)
        acc[mi][ni] = __builtin_amdgcn_mfma_f32_16x16x32_bf16(
            af[mi], bfv[ni], acc[mi][ni], 0, 0, 0);
    __syncthreads();
  }
#pragma unroll
  for (int ni = 0; ni < 4; ++ni) {
    const int colg = ny * 128 + wn * 64 + ni * 16 + lm;
    const float bv = ga.bias[colg];
#pragma unroll
    for (int mi = 0; mi < 4; ++mi) {
      const int rg = m0 + wm * 64 + mi * 16 + q * 4;
#pragma unroll
      for (int r = 0; r < 4; ++r) {
        float v = acc[mi][ni][r] + bv;
        if (ga.cbf)
          ((unsigned short*)ga.C)[(size_t)(rg + r) * ga.cs + colg] = f2b(v);
        else
          ((float*)ga.C)[(size_t)(rg + r) * ga.cs + colg] = v;
      }
    }
  }
  if (ga.vsum) {
    float* vp = ga.vsum + (size_t)(m0 >> 9) * 128;
#pragma unroll
    for (int ni = 0; ni < 4; ++ni) {
      const int colg = wn * 64 + ni * 16 + lm;
      float s = 16.f * ga.bias[colg];
#pragma unroll
      for (int mi = 0; mi < 4; ++mi)
#pragma unroll
        for (int r = 0; r < 4; ++r) s += acc[mi][ni][r];
      atomicAdd(&vp[colg], s);
    }
  }
}

// ---------------------------------------------------------------------------
// gemm_k128 v2: whole-tile single-barrier + SWAPPED-OPERAND epilogue.
//  * staging split: all 16 global loads issued first (one latency exposure),
//    then all LDS writes.
//  * mfma(bfv, af, acc): lane now holds C[row=mi*16+lm][cols=ni*16+q*4..+3]
//    (A/B fragments share a register layout, so swap needs no reload; per-
//    element dot order identical -> same numerics).
//  * packed store: 2x v_cvt_pk_bf16_f32 + 1 dwordx2 per (mi,ni): 16 stores/
//    thread (512B/instr) instead of 64 scalar u16 stores (128B/instr), and
//    32 cvt_pk instead of ~320 VALU ops of scalar f2b.
//  * vsum: shfl-reduce over the 16 row-lanes, atomics from lane lm==0 only.
// ---------------------------------------------------------------------------
#define CST 5120  // chunk stride in shorts (128 rows * 40)

__global__ __launch_bounds__(256) void gemm_k128(GArgs args) {
  const GArg ga = args.g[blockIdx.z];
  const int ny = blockIdx.y;
  __shared__ unsigned short As4[4 * CST];
  __shared__ unsigned short Ws4[4 * CST];
  const int t = threadIdx.x;
  const int lane = t & 63, q = lane >> 4, lm = lane & 15;
  const int w = t >> 6;
  const int wm = w >> 1, wn = w & 1;
  const int m0 = blockIdx.x * 128;

  // staging: thread covers rows (t>>4)+16p, col octet (t&15)*8
  const int srow = t >> 4, scol = (t & 15) * 8;
  const int sc = scol >> 5, soff = scol & 31;
  {
    const unsigned short* Ab =
        (const unsigned short*)ga.A + (size_t)(m0 + srow) * 128 + scol;
    const unsigned short* Wg =
        ga.W + (size_t)(ny * 128 + srow) * 128 + scol;
    short8 avv[8], wvv[8];
#pragma unroll
    for (int p = 0; p < 8; ++p) {
      avv[p] = *reinterpret_cast<const short8*>(Ab + (size_t)p * 16 * 128);
      wvv[p] = *reinterpret_cast<const short8*>(Wg + (size_t)p * 16 * 128);
    }
#pragma unroll
    for (int p = 0; p < 8; ++p) {
      *reinterpret_cast<short8*>(&As4[sc * CST + (srow + p * 16) * 40 + soff]) = avv[p];
      *reinterpret_cast<short8*>(&Ws4[sc * CST + (srow + p * 16) * 40 + soff]) = wvv[p];
    }
  }
  __syncthreads();

  f32x4 acc[4][4];
#pragma unroll
  for (int i = 0; i < 4; ++i)
#pragma unroll
    for (int j = 0; j < 4; ++j) acc[i][j] = (f32x4){0.f, 0.f, 0.f, 0.f};

#pragma unroll
  for (int c = 0; c < 4; ++c) {
    short8 af[4], bfv[4];
#pragma unroll
    for (int mi = 0; mi < 4; ++mi)
      af[mi] = *reinterpret_cast<const short8*>(
          &As4[c * CST + (wm * 64 + mi * 16 + lm) * 40 + q * 8]);
#pragma unroll
    for (int ni = 0; ni < 4; ++ni)
      bfv[ni] = *reinterpret_cast<const short8*>(
          &Ws4[c * CST + (wn * 64 + ni * 16 + lm) * 40 + q * 8]);
#pragma unroll
    for (int mi = 0; mi < 4; ++mi)
#pragma unroll
      for (int ni = 0; ni < 4; ++ni)
        acc[mi][ni] = __builtin_amdgcn_mfma_f32_16x16x32_bf16(
            bfv[ni], af[mi], acc[mi][ni], 0, 0, 0);  // swapped operands
  }

  // lane holds C[m0+wm*64+mi*16+lm][ny*128+wn*64+ni*16+q*4 .. +3]
#pragma unroll
  for (int ni = 0; ni < 4; ++ni) {
    const int cb = ny * 128 + wn * 64 + ni * 16 + q * 4;
    const f32x4 bv4 = *reinterpret_cast<const f32x4*>(&ga.bias[cb]);
#pragma unroll
    for (int mi = 0; mi < 4; ++mi) {
      const int rg = m0 + wm * 64 + mi * 16 + lm;
      f32x4 v = acc[mi][ni];
      v[0] += bv4[0]; v[1] += bv4[1]; v[2] += bv4[2]; v[3] += bv4[3];
      if (ga.cbf) {
        uint2v pk;
        pk[0] = cvtpk(v[0], v[1]);
        pk[1] = cvtpk(v[2], v[3]);
        *reinterpret_cast<uint2v*>(
            &((unsigned short*)ga.C)[(size_t)rg * ga.cs + cb]) = pk;
      } else {
        *reinterpret_cast<f32x4*>(
            &((float*)ga.C)[(size_t)rg * ga.cs + cb]) = v;
      }
    }
  }
  if (ga.vsum) {
    // vsum launches have ny==0, cs==128.  Per lane: 4 rows (mi) of its col;
    // reduce 16 row-lanes via shfl, atomic from lm==0 only.
    float* vp = ga.vsum + (size_t)(m0 >> 9) * 128;
#pragma unroll
    for (int ni = 0; ni < 4; ++ni) {
      const int cb = wn * 64 + ni * 16 + q * 4;
      const f32x4 bv4 = *reinterpret_cast<const f32x4*>(&ga.bias[cb]);
#pragma unroll
      for (int r = 0; r < 4; ++r) {
        float sv = (acc[0][ni][r] + acc[1][ni][r]) +
                   (acc[2][ni][r] + acc[3][ni][r]) + 4.f * bv4[r];
#pragma unroll
        for (int m = 1; m < 16; m <<= 1) sv += __shfl_xor(sv, m);
        if (lm == 0) atomicAdd(&vp[cb + r], sv);
      }
    }
  }
}

// ---------------------------------------------------------------------------
// MFMA attention v3 (probs = 1 - softmax): ctx = Vsum - softmax(QK^T/8) @ V.
// grid = (2 q-halves, 128 = b*2+h, 3 units), block = 256 (4 waves).
// PV MFMA operand-swapped: lane holds ctx[q-row=lm][d=dt*16+quad*4..+3] ->
// packed dwordx2 CTX stores (16/thread vs 64 scalar u16), 4 rcp vs 16.
// suml redistributed to the lm-row layout via a per-wave LDS buffer.
// ---------------------------------------------------------------------------
__global__ __launch_bounds__(256) void attn2(
    const unsigned short* __restrict__ QKV, const float* __restrict__ VS,
    unsigned short* __restrict__ CTX) {
  __shared__ unsigned short Vt[64 * 72];       // [d][k ^ (d&56)]
  __shared__ unsigned short Pt[4][16 * 72];    // per-wave [q][k]
  __shared__ float SB[4][4][16];               // per-wave suml by q-row
  const int t = threadIdx.x;
  const int w = t >> 6, lane = t & 63, quad = lane >> 4, lm = lane & 15;
  const int z = blockIdx.z;
  const int bh = blockIdx.y, b = bh >> 1, h = bh & 1;
  const int qbase = blockIdx.x * 256;

  const unsigned short* Qg = QKV + (size_t)(z * 3 + 0) * SZ;
  const unsigned short* Kg = QKV + (size_t)(z * 3 + 1) * SZ;
  const unsigned short* Vg = QKV + (size_t)(z * 3 + 2) * SZ;

  short8 aq[4][2];
#pragma unroll
  for (int qt = 0; qt < 4; ++qt)
#pragma unroll
    for (int c = 0; c < 2; ++c)
      aq[qt][c] = *reinterpret_cast<const short8*>(
          Qg + ((size_t)(b * SS + qbase + qt * 64 + w * 16 + lm)) * DD +
          h * 64 + c * 32 + quad * 8);

  const f32x4 czero = {0.f, 0.f, 0.f, 0.f};
  f32x4 o[4][4];  // [qt][dt]; swapped layout: reg r = d sub-index
#pragma unroll
  for (int i = 0; i < 4; ++i)
#pragma unroll
    for (int j = 0; j < 4; ++j) o[i][j] = czero;
  float suml[4][4];  // [qt][r] for q-row quad*4+r (QK layout)
#pragma unroll
  for (int i = 0; i < 4; ++i)
#pragma unroll
    for (int j = 0; j < 4; ++j) suml[i][j] = 0.f;

  const int vk = t >> 3, vd0 = (t & 7) * 8;

  for (int kt = 0; kt < 8; ++kt) {
    const int k0 = kt * 64;
    __syncthreads();  // prior Vt fully consumed (bv regs read)
#pragma unroll
    for (int i = 0; i < 2; ++i) {
      const int k = vk + i * 32;
      short8 vv = *reinterpret_cast<const short8*>(
          Vg + ((size_t)(b * SS + k0 + k)) * DD + h * 64 + vd0);
#pragma unroll
      for (int j = 0; j < 8; ++j) {
        const int d = vd0 + j;
        Vt[d * 72 + (k ^ (d & 56))] = (unsigned short)vv[j];
      }
    }
    __syncthreads();

    short8 bk[4][2];
#pragma unroll
    for (int nt = 0; nt < 4; ++nt)
#pragma unroll
      for (int c = 0; c < 2; ++c)
        bk[nt][c] = *reinterpret_cast<const short8*>(
            Kg + ((size_t)(b * SS + k0 + nt * 16 + lm)) * DD + h * 64 +
            c * 32 + quad * 8);
    short8 bvv[4][2];
#pragma unroll
    for (int dt = 0; dt < 4; ++dt) {
      const int d = dt * 16 + lm;
#pragma unroll
      for (int c = 0; c < 2; ++c)
        bvv[dt][c] = *reinterpret_cast<const short8*>(
            &Vt[d * 72 + ((c * 32 + quad * 8) ^ (d & 56))]);
    }

#pragma unroll
    for (int qt = 0; qt < 4; ++qt) {
      f32x4 sacc[4];
#pragma unroll
      for (int nt = 0; nt < 4; ++nt)
        sacc[nt] = __builtin_amdgcn_mfma_f32_16x16x32_bf16(
            aq[qt][0], bk[nt][0], czero, 0, 0, 0);
#pragma unroll
      for (int nt = 0; nt < 4; ++nt)
        sacc[nt] = __builtin_amdgcn_mfma_f32_16x16x32_bf16(
            aq[qt][1], bk[nt][1], sacc[nt], 0, 0, 0);
#pragma unroll
      for (int nt = 0; nt < 4; ++nt) {
#pragma unroll
        for (int r = 0; r < 4; ++r) {
          float p = fexp2_(sacc[nt][r]);
          suml[qt][r] += p;
          Pt[w][(quad * 4 + r) * 72 + nt * 16 + lm] = f2b_trunc(p);
        }
      }
#pragma unroll
      for (int c = 0; c < 2; ++c) {
        short8 ap = *reinterpret_cast<const short8*>(
            &Pt[w][lm * 72 + c * 32 + quad * 8]);
#pragma unroll
        for (int dt = 0; dt < 4; ++dt)
          o[qt][dt] = __builtin_amdgcn_mfma_f32_16x16x32_bf16(
              bvv[dt][c], ap, o[qt][dt], 0, 0, 0);  // swapped operands
      }
    }
  }
  // reduce suml over the 16 k-lanes, then redistribute to q-row = lm layout.
#pragma unroll
  for (int qt = 0; qt < 4; ++qt) {
#pragma unroll
    for (int r = 0; r < 4; ++r) {
#pragma unroll
      for (int m = 1; m < 16; m <<= 1)
        suml[qt][r] += __shfl_xor(suml[qt][r], m);
      if (lm == 0) SB[w][qt][quad * 4 + r] = suml[qt][r];
    }
  }
  float rsum[4];
#pragma unroll
  for (int qt = 0; qt < 4; ++qt) rsum[qt] = frcp_(SB[w][qt][lm]);

  const float* vsp = VS + (size_t)(z * BB + b) * DD + h * 64;
#pragma unroll
  for (int qt = 0; qt < 4; ++qt) {
    const int row = qbase + qt * 64 + w * 16 + lm;
    unsigned short* cp =
        CTX + (size_t)z * SZ + ((size_t)(b * SS + row)) * DD + h * 64;
#pragma unroll
    for (int dt = 0; dt < 4; ++dt) {
      const int d0 = dt * 16 + quad * 4;
      const f32x4 vs4 = *reinterpret_cast<const f32x4*>(&vsp[d0]);
      uint2v pk;
      pk[0] = cvtpk(vs4[0] - o[qt][dt][0] * rsum[qt],
                    vs4[1] - o[qt][dt][1] * rsum[qt]);
      pk[1] = cvtpk(vs4[2] - o[qt][dt][2] * rsum[qt],
                    vs4[3] - o[qt][dt][3] * rsum[qt]);
      *reinterpret_cast<uint2v*>(cp + d0) = pk;
    }
  }
}

// ---------------------------------------------------------------------------
// Fused LN pair, 4 rows/block (1 wave per row).  u32 packed loads/stores.
// ---------------------------------------------------------------------------
__global__ __launch_bounds__(256) void ln_pair(
    const unsigned short* __restrict__ DOUT, const float* __restrict__ lng,
    const float* __restrict__ lnb, unsigned short* __restrict__ GRUIN) {
  const int g = blockIdx.y;
  const int row = blockIdx.x * 4 + (threadIdx.x >> 6);
  const int t = threadIdx.x & 63;
  const int u1t[3] = {1, 2, 0};
  const int u2t[3] = {3, 5, 4};
  float outA = 0.f, outB = 0.f;
#pragma unroll
  for (int half = 0; half < 2; ++half) {
    const int u = half == 0 ? u1t[g] : u2t[g];
    const unsigned short* x = DOUT + (size_t)u * SZ + (size_t)row * DD;
    unsigned int xv = *reinterpret_cast<const unsigned int*>(x + 2 * t);
    float a = b2f((unsigned short)(xv & 0xffffu));
    float c = b2f((unsigned short)(xv >> 16));
    float s = a + c, sq = a * a + c * c;
#pragma unroll
    for (int off = 32; off > 0; off >>= 1) {
      s += __shfl_down(s, off);
      sq += __shfl_down(sq, off);
    }
    s = __shfl(s, 0); sq = __shfl(sq, 0);
    float mean = s * (1.f / 128.f);
    float var = sq * (1.f / 128.f) - mean * mean;
    float rs = rsqrtf(var + 1e-5f);
    const float* gg = lng + u * 128;
    const float* bb = lnb + u * 128;
    outA += (a - mean) * rs * gg[2 * t] + bb[2 * t];
    outB += (c - mean) * rs * gg[2 * t + 1] + bb[2 * t + 1];
  }
  unsigned short* op = GRUIN + (size_t)g * SZ + (size_t)row * DD;
  unsigned int pk = (unsigned int)f2b(0.5f * outA) |
                    ((unsigned int)f2b(0.5f * outB) << 16);
  *reinterpret_cast<unsigned int*>(op + 2 * t) = pk;
}

// ---------------------------------------------------------------------------
// GRU v10 (confirmed best: 173-175us, stable across rounds).  Do not
// restructure (v11 regressed).  grid = (16 bg, 6 rec), block = 512 (8 waves).
// ---------------------------------------------------------------------------
#define AST 136

__global__ __launch_bounds__(512, 1) void gru8(
    const unsigned short* __restrict__ GXR, const unsigned short* __restrict__ WB,
    const float* __restrict__ gbhh, float* __restrict__ HS) {
  __shared__ unsigned short Abuf[2][16 * AST];
  const int rec = blockIdx.y, bg = blockIdx.x;
  const int dir = rec & 1;
  const int t = threadIdx.x;
  const int w = t >> 6, lane = t & 63, q = lane >> 4, lm = lane & 15;
  const int o = w * 16 + lm;
  const int b = bg * 4 + q;

  short8 Bh[3][4];
  const unsigned short* whh = WB + WB_WHH + (size_t)rec * 49152;
#pragma unroll
  for (int gate = 0; gate < 3; ++gate)
#pragma unroll
    for (int c = 0; c < 4; ++c)
      Bh[gate][c] = *reinterpret_cast<const short8*>(
          whh + (size_t)(gate * 128 + o) * 128 + c * 32 + q * 8);
  const float bhn = gbhh[rec * 384 + 256 + o] * (2.f * LOG2E);
  const f32x4 czero = {0.f, 0.f, 0.f, 0.f};
  const f32x4 cbhn = {bhn, 0.f, 0.f, 0.f};

  float h = 0.f, hsum = 0.f;
  for (int i = t; i < 2 * 16 * AST; i += 512)
    (&Abuf[0][0])[i] = 0;

  // gx: 3 ushort loads/step from GXR[rec][b*512 + tt][384] at cols g*128+o.
  const unsigned short* gx0 = GXR + (size_t)rec * 12582912 +
      ((size_t)b * 512 + (dir ? 511 : 0)) * 384 + o;
  const ptrdiff_t st = dir ? -384 : 384;

  unsigned short ring[4][3];
#pragma unroll
  for (int pp = 0; pp < 4; ++pp) {
    const unsigned short* gp = gx0 + (ptrdiff_t)pp * st;
#pragma unroll
    for (int j = 0; j < 3; ++j) ring[pp][j] = gp[j * 128];
  }
  const unsigned short* pf = gx0 + (ptrdiff_t)4 * st;  // prefetch ptr (s+4)
  __syncthreads();

#pragma unroll 4
  for (int s = 0; s < SS; ++s) {
    const int p = s & 1, slot = s & 3;
    const float gxr = b2f(ring[slot][0]);
    const float gxz = b2f(ring[slot][1]);
    const float gxn = b2f(ring[slot][2]);
#pragma unroll
    for (int j = 0; j < 3; ++j) ring[slot][j] = pf[j * 128];
    pf += (s < SS - 5) ? st : 0;  // uniform-cond pointer bump, stays in-bounds

    short8 ah0 = *reinterpret_cast<const short8*>(&Abuf[p][lm * AST + 0 + q * 8]);
    short8 ah1 = *reinterpret_cast<const short8*>(&Abuf[p][lm * AST + 32 + q * 8]);
    short8 ah2 = *reinterpret_cast<const short8*>(&Abuf[p][lm * AST + 64 + q * 8]);
    short8 ah3 = *reinterpret_cast<const short8*>(&Abuf[p][lm * AST + 96 + q * 8]);
    f32x4 r0 = __builtin_amdgcn_mfma_f32_16x16x32_bf16(ah0, Bh[0][0], czero, 0, 0, 0);
    f32x4 r1 = __builtin_amdgcn_mfma_f32_16x16x32_bf16(ah2, Bh[0][2], czero, 0, 0, 0);
    f32x4 z0 = __builtin_amdgcn_mfma_f32_16x16x32_bf16(ah0, Bh[1][0], czero, 0, 0, 0);
    f32x4 z1 = __builtin_amdgcn_mfma_f32_16x16x32_bf16(ah2, Bh[1][2], czero, 0, 0, 0);
    f32x4 n0 = __builtin_amdgcn_mfma_f32_16x16x32_bf16(ah0, Bh[2][0], cbhn, 0, 0, 0);
    f32x4 n1 = __builtin_amdgcn_mfma_f32_16x16x32_bf16(ah2, Bh[2][2], czero, 0, 0, 0);
    r0 = __builtin_amdgcn_mfma_f32_16x16x32_bf16(ah1, Bh[0][1], r0, 0, 0, 0);
    r1 = __builtin_amdgcn_mfma_f32_16x16x32_bf16(ah3, Bh[0][3], r1, 0, 0, 0);
    z0 = __builtin_amdgcn_mfma_f32_16x16x32_bf16(ah1, Bh[1][1], z0, 0, 0, 0);
    z1 = __builtin_amdgcn_mfma_f32_16x16x32_bf16(ah3, Bh[1][3], z1, 0, 0, 0);
    n0 = __builtin_amdgcn_mfma_f32_16x16x32_bf16(ah1, Bh[2][1], n0, 0, 0, 0);
    n1 = __builtin_amdgcn_mfma_f32_16x16x32_bf16(ah3, Bh[2][3], n1, 0, 0, 0);

    float rr = frcp_(1.f + fexp2_(-(gxr + r0[0] + r1[0])));
    float zz = frcp_(1.f + fexp2_(-(gxz + z0[0] + z1[0])));
    float nn = 1.f - 2.f * frcp_(fexp2_(gxn + rr * (n0[0] + n1[0])) + 1.f);
    h = nn + zz * (h - nn);
    hsum += h;
    Abuf[p ^ 1][(q * 4) * AST + o] = f2b_trunc(h);
    asm volatile("s_waitcnt lgkmcnt(0)\n\ts_barrier" ::: "memory");
  }
  HS[((size_t)rec * BB + bg * 4 + q) * 128 + o] = hsum;
}

// ---------------------------------------------------------------------------
// Head: pooled -> Linear -> BN(eval) -> ReLU6 -> Linear.  grid=64, block=256.
// ---------------------------------------------------------------------------
__global__ __launch_bounds__(256) void head_kernel(
    const float* __restrict__ HS, const float* __restrict__ fW1,
    const float* __restrict__ fb1, const float* __restrict__ bng,
    const float* __restrict__ bnb, const float* __restrict__ fW2,
    const float* __restrict__ fb2, float* __restrict__ out) {
  __shared__ float pl[384];
  __shared__ float h1[256];
  int b = blockIdx.x, n = threadIdx.x;
  {
    int j = n;
    int seg = j >> 7, oo = j & 127;
    pl[j] = (HS[((size_t)seg * BB + b) * 128 + oo] +
             HS[((size_t)(seg + 3) * BB + b) * 128 + oo]) * (0.5f / 512.f);
  }
  if (n < 128) {
    int j = 256 + n;
    int seg = j >> 7, oo = j & 127;
    pl[j] = (HS[((size_t)seg * BB + b) * 128 + oo] +
             HS[((size_t)(seg + 3) * BB + b) * 128 + oo]) * (0.5f / 512.f);
  }
  __syncthreads();
  float acc = fb1[n];
  for (int k = 0; k < 384; ++k) acc += pl[k] * fW1[k * 256 + n];
  float hv = acc * rsqrtf(1.f + 1e-5f) * bng[n] + bnb[n];
  hv = fminf(fmaxf(hv, 0.f), 6.f);
  h1[n] = hv;
  __syncthreads();
  if (n < 8) {
    float a2 = fb2[n];
    for (int k = 0; k < 256; ++k) a2 += h1[k] * fW2[k * 8 + n];
    out[b * 8 + n] = a2;
  }
}

// ---------------------------------------------------------------------------
extern "C" void kernel_launch(void* const* d_in, const int* in_sizes, int n_in,
                              void* d_out, int out_size, void* d_ws,
                              size_t ws_size, hipStream_t stream) {
  (void)in_sizes; (void)n_in; (void)out_size; (void)ws_size;
  const float* text = (const float*)d_in[0];
  const float* vis  = (const float*)d_in[1];
  const float* aud  = (const float*)d_in[2];
  const float* fc1W = (const float*)d_in[3];
  const float* fc1b = (const float*)d_in[4];
  const float* fc2W = (const float*)d_in[5];
  const float* fc2b = (const float*)d_in[6];
  const float* fc3W = (const float*)d_in[7];
  const float* fc3b = (const float*)d_in[8];
  const float* Wq = (const float*)d_in[9];
  const float* bq = (const float*)d_in[10];
  const float* Wk = (const float*)d_in[11];
  const float* bk = (const float*)d_in[12];
  const float* Wv = (const float*)d_in[13];
  const float* bv = (const float*)d_in[14];
  const float* Wd = (const float*)d_in[15];
  const float* bd = (const float*)d_in[16];
  const float* lng = (const float*)d_in[17];
  const float* lnb = (const float*)d_in[18];
  const float* gWih = (const float*)d_in[19];
  const float* gWhh = (const float*)d_in[20];
  const float* gbih = (const float*)d_in[21];
  const float* gbhh = (const float*)d_in[22];
  const float* fW1 = (const float*)d_in[23];
  const float* fb1 = (const float*)d_in[24];
  const float* bng = (const float*)d_in[25];
  const float* bnb = (const float*)d_in[26];
  const float* fW2 = (const float*)d_in[27];
  const float* fb2 = (const float*)d_in[28];
  float* out = (float*)d_out;

  unsigned short* WSB = (unsigned short*)d_ws;
  unsigned short* T   = WSB;
  unsigned short* Vv  = WSB + SZ;
  unsigned short* Aa  = WSB + 2 * SZ;
  unsigned short* QKV = WSB + 3 * SZ;
  unsigned short* CTX = WSB + 12 * SZ;
  unsigned short* DOUT = WSB;
  unsigned short* GXR = WSB;              // slices 0..17 ([6][32768][384])
  unsigned short* GRUIN = WSB + 18 * SZ;  // slices 18..20
  unsigned short* WB  = WSB + 21 * SZ;
  float* VS = (float*)(WSB + 21 * SZ + 1048576);
  float* HS = VS + 6 * 64 * 128;
  float* gbihs = HS + 6 * 64 * 128;       // 2304 floats
  float* bqs = gbihs + 6 * 384;           // 768 floats

  prep_kernel<<<dim3(1024), dim3(256), 0, stream>>>(
      fc1W, fc2W, fc3W, Wq, Wk, Wv, Wd, gWih, gWhh, gbih, gbhh, bq, WB,
      gbihs, bqs);
  hipMemsetAsync(VS, 0, 6 * 64 * 128 * sizeof(float), stream);

  {
    GArgs ga{};
    ga.g[0] = {text, WB + WB_P1, fc1b, T, 300, 320, 0, 1, 128};
    ga.g[1] = {vis,  WB + WB_P2, fc2b, Vv, 35, 64, 0, 1, 128};
    ga.g[2] = {aud,  WB + WB_P3, fc3b, Aa, 74, 96, 0, 1, 128};
    gemm_b<<<dim3(256, 1, 3), dim3(256), 0, stream>>>(ga);
  }

  const int qsel[6] = {0, 2, 0, 1, 1, 2};
  const int ksel[6] = {2, 0, 1, 0, 2, 1};
  unsigned short* proj[3] = {T, Vv, Aa};

  for (int phase = 0; phase < 2; ++phase) {
    GArgs ga{};
    for (int ul = 0; ul < 3; ++ul) {
      int u = phase * 3 + ul;
      for (int op = 0; op < 3; ++op) {
        int z = ul * 3 + op;
        const float* bias = (op == 0) ? (bqs + u * 128)
                          : (op == 1) ? (bk + u * 128) : (bv + u * 128);
        float* vsum = (op == 2) ? (VS + (size_t)(phase * 3 + ul) * BB * DD)
                                : nullptr;
        ga.g[z] = {proj[op == 0 ? qsel[u] : ksel[u]],
                   WB + WB_QKVD + op * 98304 + u * 16384, bias,
                   QKV + (size_t)z * SZ, 128, 128, 1, 1, 128, vsum};
      }
    }
    gemm_k128<<<dim3(256, 1, 9), dim3(256), 0, stream>>>(ga);
    attn2<<<dim3(2, 128, 3), dim3(256), 0, stream>>>(
        QKV, VS + phase * 3 * BB * DD, CTX + (size_t)phase * 3 * SZ);
  }

  {
    GArgs ga{};
    for (int u = 0; u < 6; ++u)
      ga.g[u] = {CTX + (size_t)u * SZ, WB + WB_QKVD + 3 * 98304 + u * 16384,
                 bd + u * 128, DOUT + (size_t)u * SZ, 128, 128, 1, 1, 128};
    gemm_k128<<<dim3(256, 1, 6), dim3(256), 0, stream>>>(ga);
  }

  ln_pair<<<dim3(NROW / 4, 3), dim3(256), 0, stream>>>(DOUT, lng, lnb, GRUIN);

  // gx = GRUIN[g] @ Wih[rec]^T + gbihs[rec] -> row-major GXR (coalesced)
  {
    GArgs ga{};
    for (int r6 = 0; r6 < 6; ++r6) {
      int g = r6 >> 1;
      ga.g[r6] = {GRUIN + (size_t)g * SZ, WB + WB_WIH + r6 * 49152,
                  gbihs + r6 * 384, GXR + (size_t)r6 * 12582912,
                  128, 128, 1, 1, 384};
    }
    gemm_k128<<<dim3(256, 3, 6), dim3(256), 0, stream>>>(ga);
  }

  gru8<<<dim3(16, 6), dim3(512), 0, stream>>>(GXR, WB, gbhh, HS);
  head_kernel<<<dim3(BB), dim3(256), 0, stream>>>(HS, fW1, fb1, bng, bnb, fW2, fb2, out);
}

// Round 7
// 710.187 us; speedup vs baseline: 1.0478x; 1.0478x over previous
//
#include <hip/hip_runtime.h>
#include <hip/hip_bf16.h>

// Problem constants
#define BB 64
#define SS 512
#define DD 128
#define NROW (BB * SS)          // 32768
#define SZ ((size_t)NROW * DD)  // 4,194,304 elems per [B,S,128] slice

#define LOG2E 1.4426950408889634f
#define QSCALE (0.125f * LOG2E)

typedef __attribute__((ext_vector_type(8))) short short8;
typedef __attribute__((ext_vector_type(4))) float f32x4;

// WB (converted-weight buffer) element offsets, all bf16:
#define WB_P1 0          // fc1W^T [128][320] (K=300 pad 320)
#define WB_P2 40960      // fc2W^T [128][64]  (K=35 pad 64)
#define WB_P3 49152      // fc3W^T [128][96]  (K=74 pad 96)
#define WB_QKVD 61440    // [4 op][6 u][128 n][128 k]  (op0=Wq prescaled by QSCALE)
#define WB_WIH 454656    // [6 rec][384 n][128 k]  (prescaled by log2e/2log2e)
#define WB_WHH 749568    // [6 rec][384 n][128 k]  (prescaled by log2e/2log2e)
#define WB_TOTAL 1044480

__device__ __forceinline__ float frcp_(float x) { return __builtin_amdgcn_rcpf(x); }
__device__ __forceinline__ float fexp2_(float x) { return __builtin_amdgcn_exp2f(x); }
__device__ __forceinline__ float b2f(unsigned short u) {
  union { unsigned int i; float f; } x; x.i = ((unsigned int)u) << 16; return x.f;
}
__device__ __forceinline__ unsigned short f2b(float f) {
  __hip_bfloat16 b = __float2bfloat16(f);
  return *reinterpret_cast<unsigned short*>(&b);
}
__device__ __forceinline__ unsigned short f2b_trunc(float f) {
  union { float f; unsigned int i; } x; x.f = f; return (unsigned short)(x.i >> 16);
}

// ---------------------------------------------------------------------------
// Weight prep.  Wq prescaled by QSCALE; GRU weights prescaled by log2e (r,z)
// / 2log2e (n).  gbihs = scale*(gbih + gbhh) for r,z gates; for n gate
// gbihs = scale*gbih only (bhh_n carried by gru kernel's cbhn accumulator).
// ---------------------------------------------------------------------------
__global__ __launch_bounds__(256) void prep_kernel(
    const float* __restrict__ fc1W, const float* __restrict__ fc2W,
    const float* __restrict__ fc3W, const float* __restrict__ Wq,
    const float* __restrict__ Wk, const float* __restrict__ Wv,
    const float* __restrict__ Wd, const float* __restrict__ gWih,
    const float* __restrict__ gWhh, const float* __restrict__ gbih,
    const float* __restrict__ gbhh, const float* __restrict__ bq,
    unsigned short* __restrict__ WB, float* __restrict__ gbihs,
    float* __restrict__ bqs) {
  for (int idx = blockIdx.x * 256 + threadIdx.x; idx < WB_TOTAL;
       idx += gridDim.x * 256) {
    float v;
    if (idx < WB_P2) {
      int n = idx / 320, k = idx % 320;
      v = (k < 300) ? fc1W[k * 128 + n] : 0.f;
    } else if (idx < WB_P3) {
      int r = idx - WB_P2; int n = r >> 6, k = r & 63;
      v = (k < 35) ? fc2W[k * 128 + n] : 0.f;
    } else if (idx < WB_QKVD) {
      int r = idx - WB_P3; int n = r / 96, k = r % 96;
      v = (k < 74) ? fc3W[k * 128 + n] : 0.f;
    } else if (idx < WB_WIH) {
      int r = idx - WB_QKVD;
      int op = r / 98304; int r2 = r % 98304;
      int u = r2 >> 14; int r3 = r2 & 16383;
      int n = r3 >> 7, k = r3 & 127;
      const float* src = (op == 0) ? Wq : (op == 1) ? Wk : (op == 2) ? Wv : Wd;
      v = src[u * 16384 + k * 128 + n];
      if (op == 0) v *= QSCALE;
    } else if (idx < WB_WHH) {
      int r = idx - WB_WIH;
      int r3 = r % 49152;  // within rec: [384 n][128 k]
      int gate = (r3 >> 7) >> 7;
      v = gWih[r] * (gate < 2 ? LOG2E : 2.f * LOG2E);
    } else {
      int r = idx - WB_WHH;
      int r3 = r % 49152;
      int gate = (r3 >> 7) >> 7;
      v = gWhh[r] * (gate < 2 ? LOG2E : 2.f * LOG2E);
    }
    WB[idx] = f2b(v);
  }
  for (int idx = blockIdx.x * 256 + threadIdx.x; idx < 6 * 384;
       idx += gridDim.x * 256) {
    int gate = (idx % 384) >> 7;
    float v = gbih[idx] + (gate < 2 ? gbhh[idx] : 0.f);
    gbihs[idx] = v * (gate < 2 ? LOG2E : 2.f * LOG2E);
  }
  for (int idx = blockIdx.x * 256 + threadIdx.x; idx < 6 * 128;
       idx += gridDim.x * 256) {
    bqs[idx] = bq[idx] * QSCALE;
  }
}

// ---------------------------------------------------------------------------
// GArg: shared by all gemm kernels.  For gemm_k128g, entries are grouped in
// blocks of `gw` sharing one A tile; abf of a group's FIRST entry = number of
// live entries (nw).  W/C/bias pointers are pre-offset (no ny).
// ---------------------------------------------------------------------------
struct GArg {
  const void* A; const unsigned short* W; const float* bias; void* C;
  int Ka, Kp, abf, cbf, cs; float* vsum;
};
struct GArgs { GArg g[18]; int gw; int pad_; };

// ---------------------------------------------------------------------------
// gemm_b: loop/LDS path, used ONLY for the f32-input projections (Kp<=320).
// ---------------------------------------------------------------------------
__global__ __launch_bounds__(256) void gemm_b(GArgs args) {
  const GArg ga = args.g[blockIdx.z];
  const int ny = blockIdx.y;
  __shared__ unsigned short As[128 * 40];
  __shared__ unsigned short Ws[128 * 40];
  const int t = threadIdx.x;
  const int w = t >> 6, lane = t & 63, q = lane >> 4, lm = lane & 15;
  const int wm = w >> 1, wn = w & 1;
  const int m0 = blockIdx.x * 128;
  const int row = t >> 1, cb = (t & 1) * 16;
  f32x4 acc[4][4];
#pragma unroll
  for (int i = 0; i < 4; ++i)
#pragma unroll
    for (int j = 0; j < 4; ++j) acc[i][j] = (f32x4){0.f, 0.f, 0.f, 0.f};

  for (int kt = 0; kt < ga.Kp; kt += 32) {
    {
      const float* Ag = (const float*)ga.A + (size_t)(m0 + row) * ga.Ka + kt + cb;
      unsigned short tmp[16];
#pragma unroll
      for (int j = 0; j < 16; ++j) {
        int k = kt + cb + j;
        tmp[j] = (k < ga.Ka) ? f2b(Ag[j]) : 0;
      }
      *reinterpret_cast<short8*>(&As[row * 40 + cb]) =
          *reinterpret_cast<short8*>(&tmp[0]);
      *reinterpret_cast<short8*>(&As[row * 40 + cb + 8]) =
          *reinterpret_cast<short8*>(&tmp[8]);
    }
    {
      const unsigned short* Wg =
          ga.W + (size_t)(ny * 128 + row) * ga.Kp + kt + cb;
      short8 v0 = *reinterpret_cast<const short8*>(Wg);
      short8 v1 = *reinterpret_cast<const short8*>(Wg + 8);
      *reinterpret_cast<short8*>(&Ws[row * 40 + cb]) = v0;
      *reinterpret_cast<short8*>(&Ws[row * 40 + cb + 8]) = v1;
    }
    __syncthreads();
    short8 af[4], bfv[4];
#pragma unroll
    for (int mi = 0; mi < 4; ++mi)
      af[mi] = *reinterpret_cast<const short8*>(
          &As[(wm * 64 + mi * 16 + lm) * 40 + q * 8]);
#pragma unroll
    for (int ni = 0; ni < 4; ++ni)
      bfv[ni] = *reinterpret_cast<const short8*>(
          &Ws[(wn * 64 + ni * 16 + lm) * 40 + q * 8]);
#pragma unroll
    for (int mi = 0; mi < 4; ++mi)
#pragma unroll
      for (int ni = 0; ni < 4; ++ni)
        acc[mi][ni] = __builtin_amdgcn_mfma_f32_16x16x32_bf16(
            af[mi], bfv[ni], acc[mi][ni], 0, 0, 0);
    __syncthreads();
  }
#pragma unroll
  for (int ni = 0; ni < 4; ++ni) {
    const int colg = ny * 128 + wn * 64 + ni * 16 + lm;
    const float bv = ga.bias[colg];
#pragma unroll
    for (int mi = 0; mi < 4; ++mi) {
      const int rg = m0 + wm * 64 + mi * 16 + q * 4;
#pragma unroll
      for (int r = 0; r < 4; ++r) {
        float v = acc[mi][ni][r] + bv;
        if (ga.cbf)
          ((unsigned short*)ga.C)[(size_t)(rg + r) * ga.cs + colg] = f2b(v);
        else
          ((float*)ga.C)[(size_t)(rg + r) * ga.cs + colg] = v;
      }
    }
  }
  if (ga.vsum) {
    float* vp = ga.vsum + (size_t)(m0 >> 9) * 128;
#pragma unroll
    for (int ni = 0; ni < 4; ++ni) {
      const int colg = wn * 64 + ni * 16 + lm;
      float s = 16.f * ga.bias[colg];
#pragma unroll
      for (int mi = 0; mi < 4; ++mi)
#pragma unroll
        for (int r = 0; r < 4; ++r) s += acc[mi][ni][r];
      atomicAdd(&vp[colg], s);
    }
  }
}

// ---------------------------------------------------------------------------
// gemm_k128g: grouped whole-tile path for bf16 A, K==128 slices.
// grid z = A-group.  Stage the group's shared 128x128 A tile ONCE, then loop
// over its nw W-tiles: {stage W -> barrier -> 64 MFMA -> round-4 epilogue ->
// barrier}.  Removes the redundant A re-staging of the old per-z launches
// (QKV: A shared by 2-4 slices; GXR: by 6) -- ~29% of staged bytes -- and
// cuts block count 3-4x (fewer tails).  Epilogue/operand order/vsum are the
// round-4 (733us) versions verbatim; ny is folded into pre-offset W/C/bias.
// ---------------------------------------------------------------------------
#define CST 5120  // chunk stride in shorts (128 rows * 40)

__global__ __launch_bounds__(256) void gemm_k128g(GArgs args) {
  const int base = blockIdx.z * args.gw;
  const int nw = args.g[base].abf;
  __shared__ unsigned short As4[4 * CST];
  __shared__ unsigned short Ws4[4 * CST];
  const int t = threadIdx.x;
  const int lane = t & 63, q = lane >> 4, lm = lane & 15;
  const int w = t >> 6, wm = w >> 1, wn = w & 1;
  const int m0 = blockIdx.x * 128;

  // staging geometry: thread covers rows (t>>4)+16p, col octet (t&15)*8
  const int srow = t >> 4, scol = (t & 15) * 8;
  const int sc = scol >> 5, soff = scol & 31;

  {  // stage shared A tile once
    const unsigned short* Ab =
        (const unsigned short*)args.g[base].A + (size_t)(m0 + srow) * 128 + scol;
#pragma unroll
    for (int p = 0; p < 8; ++p) {
      short8 av = *reinterpret_cast<const short8*>(Ab + (size_t)p * 16 * 128);
      *reinterpret_cast<short8*>(&As4[sc * CST + (srow + p * 16) * 40 + soff]) = av;
    }
  }

  for (int i = 0; i < nw; ++i) {
    const GArg ge = args.g[base + i];
    if (i) __syncthreads();  // all waves done reading Ws4 of entry i-1
    {
      const unsigned short* Wg = ge.W + (size_t)srow * 128 + scol;
#pragma unroll
      for (int p = 0; p < 8; ++p) {
        short8 wv = *reinterpret_cast<const short8*>(Wg + (size_t)p * 16 * 128);
        *reinterpret_cast<short8*>(&Ws4[sc * CST + (srow + p * 16) * 40 + soff]) = wv;
      }
    }
    __syncthreads();

    f32x4 acc[4][4];
#pragma unroll
    for (int ii = 0; ii < 4; ++ii)
#pragma unroll
      for (int jj = 0; jj < 4; ++jj) acc[ii][jj] = (f32x4){0.f, 0.f, 0.f, 0.f};

#pragma unroll
    for (int c = 0; c < 4; ++c) {
      short8 af[4], bfv[4];
#pragma unroll
      for (int mi = 0; mi < 4; ++mi)
        af[mi] = *reinterpret_cast<const short8*>(
            &As4[c * CST + (wm * 64 + mi * 16 + lm) * 40 + q * 8]);
#pragma unroll
      for (int ni = 0; ni < 4; ++ni)
        bfv[ni] = *reinterpret_cast<const short8*>(
            &Ws4[c * CST + (wn * 64 + ni * 16 + lm) * 40 + q * 8]);
#pragma unroll
      for (int mi = 0; mi < 4; ++mi)
#pragma unroll
        for (int ni = 0; ni < 4; ++ni)
          acc[mi][ni] = __builtin_amdgcn_mfma_f32_16x16x32_bf16(
              af[mi], bfv[ni], acc[mi][ni], 0, 0, 0);
    }

#pragma unroll
    for (int ni = 0; ni < 4; ++ni) {
      const int colg = wn * 64 + ni * 16 + lm;
      const float bv = ge.bias[colg];
#pragma unroll
      for (int mi = 0; mi < 4; ++mi) {
        const int rg = m0 + wm * 64 + mi * 16 + q * 4;
#pragma unroll
        for (int r = 0; r < 4; ++r) {
          float v = acc[mi][ni][r] + bv;
          ((unsigned short*)ge.C)[(size_t)(rg + r) * ge.cs + colg] = f2b(v);
        }
      }
    }
    if (ge.vsum) {
      float* vp = ge.vsum + (size_t)(m0 >> 9) * 128;
#pragma unroll
      for (int ni = 0; ni < 4; ++ni) {
        const int colg = wn * 64 + ni * 16 + lm;
        float s = 16.f * ge.bias[colg];
#pragma unroll
        for (int mi = 0; mi < 4; ++mi)
#pragma unroll
          for (int r = 0; r < 4; ++r) s += acc[mi][ni][r];
        atomicAdd(&vp[colg], s);
      }
    }
  }
}

// ---------------------------------------------------------------------------
// MFMA attention v2 (probs = 1 - softmax): ctx = Vsum - softmax(QK^T/8) @ V.
// grid = (2 q-halves, 128 = b*2+h, 3 units), block = 256 (4 waves).
// (round-4 version verbatim; round-5's swapped-PV/SB variant regressed.)
// ---------------------------------------------------------------------------
__global__ __launch_bounds__(256) void attn2(
    const unsigned short* __restrict__ QKV, const float* __restrict__ VS,
    unsigned short* __restrict__ CTX) {
  __shared__ unsigned short Vt[64 * 72];       // [d][k ^ (d&56)]
  __shared__ unsigned short Pt[4][16 * 72];    // per-wave [q][k]
  const int t = threadIdx.x;
  const int w = t >> 6, lane = t & 63, quad = lane >> 4, lm = lane & 15;
  const int z = blockIdx.z;
  const int bh = blockIdx.y, b = bh >> 1, h = bh & 1;
  const int qbase = blockIdx.x * 256;

  const unsigned short* Qg = QKV + (size_t)(z * 3 + 0) * SZ;
  const unsigned short* Kg = QKV + (size_t)(z * 3 + 1) * SZ;
  const unsigned short* Vg = QKV + (size_t)(z * 3 + 2) * SZ;

  short8 aq[4][2];
#pragma unroll
  for (int qt = 0; qt < 4; ++qt)
#pragma unroll
    for (int c = 0; c < 2; ++c)
      aq[qt][c] = *reinterpret_cast<const short8*>(
          Qg + ((size_t)(b * SS + qbase + qt * 64 + w * 16 + lm)) * DD +
          h * 64 + c * 32 + quad * 8);

  const f32x4 czero = {0.f, 0.f, 0.f, 0.f};
  f32x4 o[4][4];  // [qt][dt]
#pragma unroll
  for (int i = 0; i < 4; ++i)
#pragma unroll
    for (int j = 0; j < 4; ++j) o[i][j] = czero;
  float suml[4][4];  // [qt][r]
#pragma unroll
  for (int i = 0; i < 4; ++i)
#pragma unroll
    for (int j = 0; j < 4; ++j) suml[i][j] = 0.f;

  const int vk = t >> 3, vd0 = (t & 7) * 8;

  for (int kt = 0; kt < 8; ++kt) {
    const int k0 = kt * 64;
    __syncthreads();  // prior Vt fully consumed (bv regs read)
#pragma unroll
    for (int i = 0; i < 2; ++i) {
      const int k = vk + i * 32;
      short8 vv = *reinterpret_cast<const short8*>(
          Vg + ((size_t)(b * SS + k0 + k)) * DD + h * 64 + vd0);
#pragma unroll
      for (int j = 0; j < 8; ++j) {
        const int d = vd0 + j;
        Vt[d * 72 + (k ^ (d & 56))] = (unsigned short)vv[j];
      }
    }
    __syncthreads();

    short8 bk[4][2];
#pragma unroll
    for (int nt = 0; nt < 4; ++nt)
#pragma unroll
      for (int c = 0; c < 2; ++c)
        bk[nt][c] = *reinterpret_cast<const short8*>(
            Kg + ((size_t)(b * SS + k0 + nt * 16 + lm)) * DD + h * 64 +
            c * 32 + quad * 8);
    short8 bvv[4][2];
#pragma unroll
    for (int dt = 0; dt < 4; ++dt) {
      const int d = dt * 16 + lm;
#pragma unroll
      for (int c = 0; c < 2; ++c)
        bvv[dt][c] = *reinterpret_cast<const short8*>(
            &Vt[d * 72 + ((c * 32 + quad * 8) ^ (d & 56))]);
    }

#pragma unroll
    for (int qt = 0; qt < 4; ++qt) {
      f32x4 sacc[4];
#pragma unroll
      for (int nt = 0; nt < 4; ++nt)
        sacc[nt] = __builtin_amdgcn_mfma_f32_16x16x32_bf16(
            aq[qt][0], bk[nt][0], czero, 0, 0, 0);
#pragma unroll
      for (int nt = 0; nt < 4; ++nt)
        sacc[nt] = __builtin_amdgcn_mfma_f32_16x16x32_bf16(
            aq[qt][1], bk[nt][1], sacc[nt], 0, 0, 0);
#pragma unroll
      for (int nt = 0; nt < 4; ++nt) {
#pragma unroll
        for (int r = 0; r < 4; ++r) {
          float p = fexp2_(sacc[nt][r]);
          suml[qt][r] += p;
          Pt[w][(quad * 4 + r) * 72 + nt * 16 + lm] = f2b_trunc(p);
        }
      }
#pragma unroll
      for (int c = 0; c < 2; ++c) {
        short8 ap = *reinterpret_cast<const short8*>(
            &Pt[w][lm * 72 + c * 32 + quad * 8]);
#pragma unroll
        for (int dt = 0; dt < 4; ++dt)
          o[qt][dt] = __builtin_amdgcn_mfma_f32_16x16x32_bf16(
              ap, bvv[dt][c], o[qt][dt], 0, 0, 0);
      }
    }
  }
#pragma unroll
  for (int qt = 0; qt < 4; ++qt)
#pragma unroll
    for (int r = 0; r < 4; ++r) {
#pragma unroll
      for (int m = 1; m < 16; m <<= 1)
        suml[qt][r] += __shfl_xor(suml[qt][r], m);
    }
  const float* vsp = VS + (size_t)(z * BB + b) * DD + h * 64;
#pragma unroll
  for (int qt = 0; qt < 4; ++qt)
#pragma unroll
    for (int dt = 0; dt < 4; ++dt) {
      const int col = dt * 16 + lm;
      const float vs = vsp[col];
#pragma unroll
      for (int r = 0; r < 4; ++r) {
        const int row = qbase + qt * 64 + w * 16 + quad * 4 + r;
        CTX[(size_t)z * SZ + ((size_t)(b * SS + row)) * DD + h * 64 + col] =
            f2b(vs - o[qt][dt][r] * frcp_(suml[qt][r]));
      }
    }
}

// ---------------------------------------------------------------------------
// Fused LN pair, 4 rows/block (1 wave per row).  u32 packed loads/stores.
// ---------------------------------------------------------------------------
__global__ __launch_bounds__(256) void ln_pair(
    const unsigned short* __restrict__ DOUT, const float* __restrict__ lng,
    const float* __restrict__ lnb, unsigned short* __restrict__ GRUIN) {
  const int g = blockIdx.y;
  const int row = blockIdx.x * 4 + (threadIdx.x >> 6);
  const int t = threadIdx.x & 63;
  const int u1t[3] = {1, 2, 0};
  const int u2t[3] = {3, 5, 4};
  float outA = 0.f, outB = 0.f;
#pragma unroll
  for (int half = 0; half < 2; ++half) {
    const int u = half == 0 ? u1t[g] : u2t[g];
    const unsigned short* x = DOUT + (size_t)u * SZ + (size_t)row * DD;
    unsigned int xv = *reinterpret_cast<const unsigned int*>(x + 2 * t);
    float a = b2f((unsigned short)(xv & 0xffffu));
    float c = b2f((unsigned short)(xv >> 16));
    float s = a + c, sq = a * a + c * c;
#pragma unroll
    for (int off = 32; off > 0; off >>= 1) {
      s += __shfl_down(s, off);
      sq += __shfl_down(sq, off);
    }
    s = __shfl(s, 0); sq = __shfl(sq, 0);
    float mean = s * (1.f / 128.f);
    float var = sq * (1.f / 128.f) - mean * mean;
    float rs = rsqrtf(var + 1e-5f);
    const float* gg = lng + u * 128;
    const float* bb = lnb + u * 128;
    outA += (a - mean) * rs * gg[2 * t] + bb[2 * t];
    outB += (c - mean) * rs * gg[2 * t + 1] + bb[2 * t + 1];
  }
  unsigned short* op = GRUIN + (size_t)g * SZ + (size_t)row * DD;
  unsigned int pk = (unsigned int)f2b(0.5f * outA) |
                    ((unsigned int)f2b(0.5f * outB) << 16);
  *reinterpret_cast<unsigned int*>(op + 2 * t) = pk;
}

// ---------------------------------------------------------------------------
// GRU v10 (confirmed best: 173-175us, stable across rounds).  Do not
// restructure (v11 regressed).  grid = (16 bg, 6 rec), block = 512 (8 waves).
// ---------------------------------------------------------------------------
#define AST 136

__global__ __launch_bounds__(512, 1) void gru8(
    const unsigned short* __restrict__ GXR, const unsigned short* __restrict__ WB,
    const float* __restrict__ gbhh, float* __restrict__ HS) {
  __shared__ unsigned short Abuf[2][16 * AST];
  const int rec = blockIdx.y, bg = blockIdx.x;
  const int dir = rec & 1;
  const int t = threadIdx.x;
  const int w = t >> 6, lane = t & 63, q = lane >> 4, lm = lane & 15;
  const int o = w * 16 + lm;
  const int b = bg * 4 + q;

  short8 Bh[3][4];
  const unsigned short* whh = WB + WB_WHH + (size_t)rec * 49152;
#pragma unroll
  for (int gate = 0; gate < 3; ++gate)
#pragma unroll
    for (int c = 0; c < 4; ++c)
      Bh[gate][c] = *reinterpret_cast<const short8*>(
          whh + (size_t)(gate * 128 + o) * 128 + c * 32 + q * 8);
  const float bhn = gbhh[rec * 384 + 256 + o] * (2.f * LOG2E);
  const f32x4 czero = {0.f, 0.f, 0.f, 0.f};
  const f32x4 cbhn = {bhn, 0.f, 0.f, 0.f};

  float h = 0.f, hsum = 0.f;
  for (int i = t; i < 2 * 16 * AST; i += 512)
    (&Abuf[0][0])[i] = 0;

  // gx: 3 ushort loads/step from GXR[rec][b*512 + tt][384] at cols g*128+o.
  const unsigned short* gx0 = GXR + (size_t)rec * 12582912 +
      ((size_t)b * 512 + (dir ? 511 : 0)) * 384 + o;
  const ptrdiff_t st = dir ? -384 : 384;

  unsigned short ring[4][3];
#pragma unroll
  for (int pp = 0; pp < 4; ++pp) {
    const unsigned short* gp = gx0 + (ptrdiff_t)pp * st;
#pragma unroll
    for (int j = 0; j < 3; ++j) ring[pp][j] = gp[j * 128];
  }
  const unsigned short* pf = gx0 + (ptrdiff_t)4 * st;  // prefetch ptr (s+4)
  __syncthreads();

#pragma unroll 4
  for (int s = 0; s < SS; ++s) {
    const int p = s & 1, slot = s & 3;
    const float gxr = b2f(ring[slot][0]);
    const float gxz = b2f(ring[slot][1]);
    const float gxn = b2f(ring[slot][2]);
#pragma unroll
    for (int j = 0; j < 3; ++j) ring[slot][j] = pf[j * 128];
    pf += (s < SS - 5) ? st : 0;  // uniform-cond pointer bump, stays in-bounds

    short8 ah0 = *reinterpret_cast<const short8*>(&Abuf[p][lm * AST + 0 + q * 8]);
    short8 ah1 = *reinterpret_cast<const short8*>(&Abuf[p][lm * AST + 32 + q * 8]);
    short8 ah2 = *reinterpret_cast<const short8*>(&Abuf[p][lm * AST + 64 + q * 8]);
    short8 ah3 = *reinterpret_cast<const short8*>(&Abuf[p][lm * AST + 96 + q * 8]);
    f32x4 r0 = __builtin_amdgcn_mfma_f32_16x16x32_bf16(ah0, Bh[0][0], czero, 0, 0, 0);
    f32x4 r1 = __builtin_amdgcn_mfma_f32_16x16x32_bf16(ah2, Bh[0][2], czero, 0, 0, 0);
    f32x4 z0 = __builtin_amdgcn_mfma_f32_16x16x32_bf16(ah0, Bh[1][0], czero, 0, 0, 0);
    f32x4 z1 = __builtin_amdgcn_mfma_f32_16x16x32_bf16(ah2, Bh[1][2], czero, 0, 0, 0);
    f32x4 n0 = __builtin_amdgcn_mfma_f32_16x16x32_bf16(ah0, Bh[2][0], cbhn, 0, 0, 0);
    f32x4 n1 = __builtin_amdgcn_mfma_f32_16x16x32_bf16(ah2, Bh[2][2], czero, 0, 0, 0);
    r0 = __builtin_amdgcn_mfma_f32_16x16x32_bf16(ah1, Bh[0][1], r0, 0, 0, 0);
    r1 = __builtin_amdgcn_mfma_f32_16x16x32_bf16(ah3, Bh[0][3], r1, 0, 0, 0);
    z0 = __builtin_amdgcn_mfma_f32_16x16x32_bf16(ah1, Bh[1][1], z0, 0, 0, 0);
    z1 = __builtin_amdgcn_mfma_f32_16x16x32_bf16(ah3, Bh[1][3], z1, 0, 0, 0);
    n0 = __builtin_amdgcn_mfma_f32_16x16x32_bf16(ah1, Bh[2][1], n0, 0, 0, 0);
    n1 = __builtin_amdgcn_mfma_f32_16x16x32_bf16(ah3, Bh[2][3], n1, 0, 0, 0);

    float rr = frcp_(1.f + fexp2_(-(gxr + r0[0] + r1[0])));
    float zz = frcp_(1.f + fexp2_(-(gxz + z0[0] + z1[0])));
    float nn = 1.f - 2.f * frcp_(fexp2_(gxn + rr * (n0[0] + n1[0])) + 1.f);
    h = nn + zz * (h - nn);
    hsum += h;
    Abuf[p ^ 1][(q * 4) * AST + o] = f2b_trunc(h);
    asm volatile("s_waitcnt lgkmcnt(0)\n\ts_barrier" ::: "memory");
  }
  HS[((size_t)rec * BB + bg * 4 + q) * 128 + o] = hsum;
}

// ---------------------------------------------------------------------------
// Head: pooled -> Linear -> BN(eval) -> ReLU6 -> Linear.  grid=64, block=256.
// ---------------------------------------------------------------------------
__global__ __launch_bounds__(256) void head_kernel(
    const float* __restrict__ HS, const float* __restrict__ fW1,
    const float* __restrict__ fb1, const float* __restrict__ bng,
    const float* __restrict__ bnb, const float* __restrict__ fW2,
    const float* __restrict__ fb2, float* __restrict__ out) {
  __shared__ float pl[384];
  __shared__ float h1[256];
  int b = blockIdx.x, n = threadIdx.x;
  {
    int j = n;
    int seg = j >> 7, oo = j & 127;
    pl[j] = (HS[((size_t)seg * BB + b) * 128 + oo] +
             HS[((size_t)(seg + 3) * BB + b) * 128 + oo]) * (0.5f / 512.f);
  }
  if (n < 128) {
    int j = 256 + n;
    int seg = j >> 7, oo = j & 127;
    pl[j] = (HS[((size_t)seg * BB + b) * 128 + oo] +
             HS[((size_t)(seg + 3) * BB + b) * 128 + oo]) * (0.5f / 512.f);
  }
  __syncthreads();
  float acc = fb1[n];
  for (int k = 0; k < 384; ++k) acc += pl[k] * fW1[k * 256 + n];
  float hv = acc * rsqrtf(1.f + 1e-5f) * bng[n] + bnb[n];
  hv = fminf(fmaxf(hv, 0.f), 6.f);
  h1[n] = hv;
  __syncthreads();
  if (n < 8) {
    float a2 = fb2[n];
    for (int k = 0; k < 256; ++k) a2 += h1[k] * fW2[k * 8 + n];
    out[b * 8 + n] = a2;
  }
}

// ---------------------------------------------------------------------------
extern "C" void kernel_launch(void* const* d_in, const int* in_sizes, int n_in,
                              void* d_out, int out_size, void* d_ws,
                              size_t ws_size, hipStream_t stream) {
  (void)in_sizes; (void)n_in; (void)out_size; (void)ws_size;
  const float* text = (const float*)d_in[0];
  const float* vis  = (const float*)d_in[1];
  const float* aud  = (const float*)d_in[2];
  const float* fc1W = (const float*)d_in[3];
  const float* fc1b = (const float*)d_in[4];
  const float* fc2W = (const float*)d_in[5];
  const float* fc2b = (const float*)d_in[6];
  const float* fc3W = (const float*)d_in[7];
  const float* fc3b = (const float*)d_in[8];
  const float* Wq = (const float*)d_in[9];
  const float* bq = (const float*)d_in[10];
  const float* Wk = (const float*)d_in[11];
  const float* bk = (const float*)d_in[12];
  const float* Wv = (const float*)d_in[13];
  const float* bv = (const float*)d_in[14];
  const float* Wd = (const float*)d_in[15];
  const float* bd = (const float*)d_in[16];
  const float* lng = (const float*)d_in[17];
  const float* lnb = (const float*)d_in[18];
  const float* gWih = (const float*)d_in[19];
  const float* gWhh = (const float*)d_in[20];
  const float* gbih = (const float*)d_in[21];
  const float* gbhh = (const float*)d_in[22];
  const float* fW1 = (const float*)d_in[23];
  const float* fb1 = (const float*)d_in[24];
  const float* bng = (const float*)d_in[25];
  const float* bnb = (const float*)d_in[26];
  const float* fW2 = (const float*)d_in[27];
  const float* fb2 = (const float*)d_in[28];
  float* out = (float*)d_out;

  unsigned short* WSB = (unsigned short*)d_ws;
  unsigned short* T   = WSB;
  unsigned short* Vv  = WSB + SZ;
  unsigned short* Aa  = WSB + 2 * SZ;
  unsigned short* QKV = WSB + 3 * SZ;
  unsigned short* CTX = WSB + 12 * SZ;
  unsigned short* DOUT = WSB;
  unsigned short* GXR = WSB;              // slices 0..17 ([6][32768][384])
  unsigned short* GRUIN = WSB + 18 * SZ;  // slices 18..20
  unsigned short* WB  = WSB + 21 * SZ;
  float* VS = (float*)(WSB + 21 * SZ + 1048576);
  float* HS = VS + 6 * 64 * 128;
  float* gbihs = HS + 6 * 64 * 128;       // 2304 floats
  float* bqs = gbihs + 6 * 384;           // 768 floats

  prep_kernel<<<dim3(1024), dim3(256), 0, stream>>>(
      fc1W, fc2W, fc3W, Wq, Wk, Wv, Wd, gWih, gWhh, gbih, gbhh, bq, WB,
      gbihs, bqs);
  hipMemsetAsync(VS, 0, 6 * 64 * 128 * sizeof(float), stream);

  {
    GArgs ga{};
    ga.g[0] = {text, WB + WB_P1, fc1b, T, 300, 320, 0, 1, 128};
    ga.g[1] = {vis,  WB + WB_P2, fc2b, Vv, 35, 64, 0, 1, 128};
    ga.g[2] = {aud,  WB + WB_P3, fc3b, Aa, 74, 96, 0, 1, 128};
    gemm_b<<<dim3(256, 1, 3), dim3(256), 0, stream>>>(ga);
  }

  const int qsel[6] = {0, 2, 0, 1, 1, 2};
  const int ksel[6] = {2, 0, 1, 0, 2, 1};
  unsigned short* proj[3] = {T, Vv, Aa};

  for (int phase = 0; phase < 2; ++phase) {
    // Grouped QKV: 3 A-groups (one per proj source), 2-4 W-tiles each.
    GArgs ga{};
    ga.gw = 4;
    int cnt[3] = {0, 0, 0};
    for (int ul = 0; ul < 3; ++ul) {
      int u = phase * 3 + ul;
      for (int op = 0; op < 3; ++op) {
        int a = (op == 0) ? qsel[u] : ksel[u];
        int z = ul * 3 + op;
        const float* bias = (op == 0) ? (bqs + u * 128)
                          : (op == 1) ? (bk + u * 128) : (bv + u * 128);
        float* vsum = (op == 2) ? (VS + (size_t)u * BB * DD) : nullptr;
        ga.g[a * 4 + cnt[a]] = {proj[a],
                                WB + WB_QKVD + op * 98304 + u * 16384, bias,
                                QKV + (size_t)z * SZ, 128, 128, 0, 1, 128,
                                vsum};
        cnt[a]++;
      }
    }
    for (int a = 0; a < 3; ++a) ga.g[a * 4].abf = cnt[a];
    gemm_k128g<<<dim3(256, 1, 3), dim3(256), 0, stream>>>(ga);
    attn2<<<dim3(2, 128, 3), dim3(256), 0, stream>>>(
        QKV, VS + phase * 3 * BB * DD, CTX + (size_t)phase * 3 * SZ);
  }

  {
    // Dense: no A sharing -> 6 singleton groups (gw=1, nw=1 == round-4 path).
    GArgs ga{};
    ga.gw = 1;
    for (int u = 0; u < 6; ++u)
      ga.g[u] = {CTX + (size_t)u * SZ, WB + WB_QKVD + 3 * 98304 + u * 16384,
                 bd + u * 128, DOUT + (size_t)u * SZ, 128, 128, 1, 1, 128};
    gemm_k128g<<<dim3(256, 1, 6), dim3(256), 0, stream>>>(ga);
  }

  ln_pair<<<dim3(NROW / 4, 3), dim3(256), 0, stream>>>(DOUT, lng, lnb, GRUIN);

  // gx = GRUIN[g] @ Wih[rec]^T + gbihs[rec] -> row-major GXR (coalesced).
  // Grouped: 3 A-groups (one per GRUIN slice) x 6 W-tiles (2 rec x 3 ny).
  {
    GArgs ga{};
    ga.gw = 6;
    for (int g = 0; g < 3; ++g) {
      for (int i = 0; i < 6; ++i) {
        int dr = i / 3, ny = i % 3, r6 = g * 2 + dr;
        ga.g[g * 6 + i] = {GRUIN + (size_t)g * SZ,
                           WB + WB_WIH + r6 * 49152 + ny * 16384,
                           gbihs + r6 * 384 + ny * 128,
                           GXR + (size_t)r6 * 12582912 + ny * 128,
                           128, 128, (i == 0) ? 6 : 0, 1, 384, nullptr};
      }
    }
    gemm_k128g<<<dim3(256, 1, 3), dim3(256), 0, stream>>>(ga);
  }

  gru8<<<dim3(16, 6), dim3(512), 0, stream>>>(GXR, WB, gbhh, HS);
  head_kernel<<<dim3(BB), dim3(256), 0, stream>>>(HS, fW1, fb1, bng, bnb, fW2, fb2, out);
}

// Round 8
// 695.959 us; speedup vs baseline: 1.0692x; 1.0204x over previous
//
#include <hip/hip_runtime.h>
#include <hip/hip_bf16.h>

// Problem constants
#define BB 64
#define SS 512
#define DD 128
#define NROW (BB * SS)          // 32768
#define SZ ((size_t)NROW * DD)  // 4,194,304 elems per [B,S,128] slice

#define LOG2E 1.4426950408889634f
#define QSCALE (0.125f * LOG2E)

typedef __attribute__((ext_vector_type(8))) short short8;
typedef __attribute__((ext_vector_type(4))) float f32x4;

// WB (converted-weight buffer) element offsets, all bf16:
#define WB_P1 0          // fc1W^T [128][320] (K=300 pad 320)
#define WB_P2 40960      // fc2W^T [128][64]  (K=35 pad 64)
#define WB_P3 49152      // fc3W^T [128][96]  (K=74 pad 96)
#define WB_QKVD 61440    // [4 op][6 u][128 n][128 k]  (op0=Wq prescaled by QSCALE)
#define WB_WIH 454656    // [6 rec][384 n][128 k]  (prescaled by log2e/2log2e)
#define WB_WHH 749568    // [6 rec][384 n][128 k]  (prescaled by log2e/2log2e)
#define WB_TOTAL 1044480

__device__ __forceinline__ float frcp_(float x) { return __builtin_amdgcn_rcpf(x); }
__device__ __forceinline__ float fexp2_(float x) { return __builtin_amdgcn_exp2f(x); }
__device__ __forceinline__ float b2f(unsigned short u) {
  union { unsigned int i; float f; } x; x.i = ((unsigned int)u) << 16; return x.f;
}
__device__ __forceinline__ unsigned short f2b(float f) {
  __hip_bfloat16 b = __float2bfloat16(f);
  return *reinterpret_cast<unsigned short*>(&b);
}
__device__ __forceinline__ unsigned short f2b_trunc(float f) {
  union { float f; unsigned int i; } x; x.f = f; return (unsigned short)(x.i >> 16);
}

// ---------------------------------------------------------------------------
// Weight prep.  Wq prescaled by QSCALE; GRU weights prescaled by log2e (r,z)
// / 2log2e (n).  gbihs = scale*(gbih + gbhh) for r,z gates; for n gate
// gbihs = scale*gbih only (bhh_n carried by gru kernel's cbhn accumulator).
// ---------------------------------------------------------------------------
__global__ __launch_bounds__(256) void prep_kernel(
    const float* __restrict__ fc1W, const float* __restrict__ fc2W,
    const float* __restrict__ fc3W, const float* __restrict__ Wq,
    const float* __restrict__ Wk, const float* __restrict__ Wv,
    const float* __restrict__ Wd, const float* __restrict__ gWih,
    const float* __restrict__ gWhh, const float* __restrict__ gbih,
    const float* __restrict__ gbhh, const float* __restrict__ bq,
    unsigned short* __restrict__ WB, float* __restrict__ gbihs,
    float* __restrict__ bqs) {
  for (int idx = blockIdx.x * 256 + threadIdx.x; idx < WB_TOTAL;
       idx += gridDim.x * 256) {
    float v;
    if (idx < WB_P2) {
      int n = idx / 320, k = idx % 320;
      v = (k < 300) ? fc1W[k * 128 + n] : 0.f;
    } else if (idx < WB_P3) {
      int r = idx - WB_P2; int n = r >> 6, k = r & 63;
      v = (k < 35) ? fc2W[k * 128 + n] : 0.f;
    } else if (idx < WB_QKVD) {
      int r = idx - WB_P3; int n = r / 96, k = r % 96;
      v = (k < 74) ? fc3W[k * 128 + n] : 0.f;
    } else if (idx < WB_WIH) {
      int r = idx - WB_QKVD;
      int op = r / 98304; int r2 = r % 98304;
      int u = r2 >> 14; int r3 = r2 & 16383;
      int n = r3 >> 7, k = r3 & 127;
      const float* src = (op == 0) ? Wq : (op == 1) ? Wk : (op == 2) ? Wv : Wd;
      v = src[u * 16384 + k * 128 + n];
      if (op == 0) v *= QSCALE;
    } else if (idx < WB_WHH) {
      int r = idx - WB_WIH;
      int r3 = r % 49152;  // within rec: [384 n][128 k]
      int gate = (r3 >> 7) >> 7;
      v = gWih[r] * (gate < 2 ? LOG2E : 2.f * LOG2E);
    } else {
      int r = idx - WB_WHH;
      int r3 = r % 49152;
      int gate = (r3 >> 7) >> 7;
      v = gWhh[r] * (gate < 2 ? LOG2E : 2.f * LOG2E);
    }
    WB[idx] = f2b(v);
  }
  for (int idx = blockIdx.x * 256 + threadIdx.x; idx < 6 * 384;
       idx += gridDim.x * 256) {
    int gate = (idx % 384) >> 7;
    float v = gbih[idx] + (gate < 2 ? gbhh[idx] : 0.f);
    gbihs[idx] = v * (gate < 2 ? LOG2E : 2.f * LOG2E);
  }
  for (int idx = blockIdx.x * 256 + threadIdx.x; idx < 6 * 128;
       idx += gridDim.x * 256) {
    bqs[idx] = bq[idx] * QSCALE;
  }
}

// ---------------------------------------------------------------------------
// GArg: shared by all gemm kernels.  For gemm_k128g, entries are grouped in
// blocks of `gw` sharing one A tile; abf of a group's FIRST entry = number of
// live entries (nw).  For gemm_proj, abf=1 marks 16B-aligned f32 A rows
// (Ka%4==0) -> float4 staging loads.
// ---------------------------------------------------------------------------
struct GArg {
  const void* A; const unsigned short* W; const float* bias; void* C;
  int Ka, Kp, abf, cbf, cs; float* vsum;
};
struct GArgs { GArg g[18]; int gw; int pad_; };

#define CST 5120  // chunk stride in shorts (128 rows * 40)

// ---------------------------------------------------------------------------
// gemm_proj: staged whole-tile path for the f32-input projections.
// Stages of up to 96 k-cols (3 chunks, 60KB LDS total): {stage A(f32->bf16,
// float4-vectorized when abf) + W -> barrier -> nc x 16 MFMA -> barrier}.
// text K=320: 4 stages = 8 barriers (vs 20 in the old per-32 loop); vis/aud
// are single-stage.  Chunked LDS layout + MFMA order identical to the old
// gemm_b (k ascending, acc carried) -> bit-identical C.
// ---------------------------------------------------------------------------
__global__ __launch_bounds__(256) void gemm_proj(GArgs args) {
  const GArg ga = args.g[blockIdx.z];
  __shared__ unsigned short As[3 * CST];
  __shared__ unsigned short Ws[3 * CST];
  const int t = threadIdx.x;
  const int lane = t & 63, q = lane >> 4, lm = lane & 15;
  const int w = t >> 6, wm = w >> 1, wn = w & 1;
  const int m0 = blockIdx.x * 128;
  const int row = t >> 1, half = t & 1;

  f32x4 acc[4][4];
#pragma unroll
  for (int i = 0; i < 4; ++i)
#pragma unroll
    for (int j = 0; j < 4; ++j) acc[i][j] = (f32x4){0.f, 0.f, 0.f, 0.f};

  const float* Ab = (const float*)ga.A + (size_t)(m0 + row) * ga.Ka;
  const unsigned short* Wb = ga.W + (size_t)row * ga.Kp;

  for (int k0 = 0; k0 < ga.Kp; k0 += 96) {
    const int SW = (ga.Kp - k0 < 96) ? (ga.Kp - k0) : 96;  // 96/64/32, mult 32
    const int hw = SW >> 1;                                // 48/32/16 cols/thread
    const int cbase = half * hw;
    if (k0) __syncthreads();  // prior stage fully consumed

    if (ga.abf) {
      // 16B-aligned rows, Ka%4==0: whole-granule masking, float4 loads.
#pragma unroll 4
      for (int j = 0; j < hw; j += 4) {
        const int cg = k0 + cbase + j;
        float4 v = {0.f, 0.f, 0.f, 0.f};
        if (cg + 4 <= ga.Ka) v = *reinterpret_cast<const float4*>(Ab + cg);
        const int cc = cbase + j, lc = cc >> 5, co = cc & 31;
        unsigned short tp[4] = {f2b(v.x), f2b(v.y), f2b(v.z), f2b(v.w)};
        *reinterpret_cast<unsigned long long*>(&As[lc * CST + row * 40 + co]) =
            *reinterpret_cast<unsigned long long*>(tp);
      }
    } else {
      // misaligned rows (vis/aud): scalar masked loads (single-stage slices).
#pragma unroll 4
      for (int j = 0; j < hw; j += 4) {
        const int cg = k0 + cbase + j;
        unsigned short tp[4];
#pragma unroll
        for (int e = 0; e < 4; ++e)
          tp[e] = (cg + e < ga.Ka) ? f2b(Ab[cg + e]) : (unsigned short)0;
        const int cc = cbase + j, lc = cc >> 5, co = cc & 31;
        *reinterpret_cast<unsigned long long*>(&As[lc * CST + row * 40 + co]) =
            *reinterpret_cast<unsigned long long*>(tp);
      }
    }
    // W stage: bf16, rows are 16B-multiples (Kp mult of 32).
#pragma unroll 2
    for (int j = 0; j < hw; j += 8) {
      const int cg = k0 + cbase + j;
      short8 v = *reinterpret_cast<const short8*>(Wb + cg);
      const int cc = cbase + j, lc = cc >> 5, co = cc & 31;
      *reinterpret_cast<short8*>(&Ws[lc * CST + row * 40 + co]) = v;
    }
    __syncthreads();

    const int nc = SW >> 5;
    for (int c = 0; c < nc; ++c) {
      short8 af[4], bfv[4];
#pragma unroll
      for (int mi = 0; mi < 4; ++mi)
        af[mi] = *reinterpret_cast<const short8*>(
            &As[c * CST + (wm * 64 + mi * 16 + lm) * 40 + q * 8]);
#pragma unroll
      for (int ni = 0; ni < 4; ++ni)
        bfv[ni] = *reinterpret_cast<const short8*>(
            &Ws[c * CST + (wn * 64 + ni * 16 + lm) * 40 + q * 8]);
#pragma unroll
      for (int mi = 0; mi < 4; ++mi)
#pragma unroll
        for (int ni = 0; ni < 4; ++ni)
          acc[mi][ni] = __builtin_amdgcn_mfma_f32_16x16x32_bf16(
              af[mi], bfv[ni], acc[mi][ni], 0, 0, 0);
    }
  }

#pragma unroll
  for (int ni = 0; ni < 4; ++ni) {
    const int colg = wn * 64 + ni * 16 + lm;
    const float bv = ga.bias[colg];
#pragma unroll
    for (int mi = 0; mi < 4; ++mi) {
      const int rg = m0 + wm * 64 + mi * 16 + q * 4;
#pragma unroll
      for (int r = 0; r < 4; ++r) {
        float v = acc[mi][ni][r] + bv;
        ((unsigned short*)ga.C)[(size_t)(rg + r) * ga.cs + colg] = f2b(v);
      }
    }
  }
}

// ---------------------------------------------------------------------------
// gemm_k128g: grouped whole-tile path for bf16 A, K==128 slices.
// grid z = A-group.  Stage the group's shared 128x128 A tile ONCE, then loop
// over its nw W-tiles: {stage W -> barrier -> 64 MFMA -> round-4 epilogue ->
// barrier}.  (R7: -23us vs per-z launches; A-restage bytes -29%.)
// ---------------------------------------------------------------------------
__global__ __launch_bounds__(256) void gemm_k128g(GArgs args) {
  const int base = blockIdx.z * args.gw;
  const int nw = args.g[base].abf;
  __shared__ unsigned short As4[4 * CST];
  __shared__ unsigned short Ws4[4 * CST];
  const int t = threadIdx.x;
  const int lane = t & 63, q = lane >> 4, lm = lane & 15;
  const int w = t >> 6, wm = w >> 1, wn = w & 1;
  const int m0 = blockIdx.x * 128;

  // staging geometry: thread covers rows (t>>4)+16p, col octet (t&15)*8
  const int srow = t >> 4, scol = (t & 15) * 8;
  const int sc = scol >> 5, soff = scol & 31;

  {  // stage shared A tile once
    const unsigned short* Ab =
        (const unsigned short*)args.g[base].A + (size_t)(m0 + srow) * 128 + scol;
#pragma unroll
    for (int p = 0; p < 8; ++p) {
      short8 av = *reinterpret_cast<const short8*>(Ab + (size_t)p * 16 * 128);
      *reinterpret_cast<short8*>(&As4[sc * CST + (srow + p * 16) * 40 + soff]) = av;
    }
  }

  for (int i = 0; i < nw; ++i) {
    const GArg ge = args.g[base + i];
    if (i) __syncthreads();  // all waves done reading Ws4 of entry i-1
    {
      const unsigned short* Wg = ge.W + (size_t)srow * 128 + scol;
#pragma unroll
      for (int p = 0; p < 8; ++p) {
        short8 wv = *reinterpret_cast<const short8*>(Wg + (size_t)p * 16 * 128);
        *reinterpret_cast<short8*>(&Ws4[sc * CST + (srow + p * 16) * 40 + soff]) = wv;
      }
    }
    __syncthreads();

    f32x4 acc[4][4];
#pragma unroll
    for (int ii = 0; ii < 4; ++ii)
#pragma unroll
      for (int jj = 0; jj < 4; ++jj) acc[ii][jj] = (f32x4){0.f, 0.f, 0.f, 0.f};

#pragma unroll
    for (int c = 0; c < 4; ++c) {
      short8 af[4], bfv[4];
#pragma unroll
      for (int mi = 0; mi < 4; ++mi)
        af[mi] = *reinterpret_cast<const short8*>(
            &As4[c * CST + (wm * 64 + mi * 16 + lm) * 40 + q * 8]);
#pragma unroll
      for (int ni = 0; ni < 4; ++ni)
        bfv[ni] = *reinterpret_cast<const short8*>(
            &Ws4[c * CST + (wn * 64 + ni * 16 + lm) * 40 + q * 8]);
#pragma unroll
      for (int mi = 0; mi < 4; ++mi)
#pragma unroll
        for (int ni = 0; ni < 4; ++ni)
          acc[mi][ni] = __builtin_amdgcn_mfma_f32_16x16x32_bf16(
              af[mi], bfv[ni], acc[mi][ni], 0, 0, 0);
    }

#pragma unroll
    for (int ni = 0; ni < 4; ++ni) {
      const int colg = wn * 64 + ni * 16 + lm;
      const float bv = ge.bias[colg];
#pragma unroll
      for (int mi = 0; mi < 4; ++mi) {
        const int rg = m0 + wm * 64 + mi * 16 + q * 4;
#pragma unroll
        for (int r = 0; r < 4; ++r) {
          float v = acc[mi][ni][r] + bv;
          ((unsigned short*)ge.C)[(size_t)(rg + r) * ge.cs + colg] = f2b(v);
        }
      }
    }
    if (ge.vsum) {
      float* vp = ge.vsum + (size_t)(m0 >> 9) * 128;
#pragma unroll
      for (int ni = 0; ni < 4; ++ni) {
        const int colg = wn * 64 + ni * 16 + lm;
        float s = 16.f * ge.bias[colg];
#pragma unroll
        for (int mi = 0; mi < 4; ++mi)
#pragma unroll
          for (int r = 0; r < 4; ++r) s += acc[mi][ni][r];
        atomicAdd(&vp[colg], s);
      }
    }
  }
}

// ---------------------------------------------------------------------------
// MFMA attention v2 (probs = 1 - softmax): ctx = Vsum - softmax(QK^T/8) @ V.
// grid = (2 q-halves, 128 = b*2+h, 3 units), block = 256 (4 waves).
// (round-4 version verbatim; round-5's swapped-PV/SB variant regressed.)
// ---------------------------------------------------------------------------
__global__ __launch_bounds__(256) void attn2(
    const unsigned short* __restrict__ QKV, const float* __restrict__ VS,
    unsigned short* __restrict__ CTX) {
  __shared__ unsigned short Vt[64 * 72];       // [d][k ^ (d&56)]
  __shared__ unsigned short Pt[4][16 * 72];    // per-wave [q][k]
  const int t = threadIdx.x;
  const int w = t >> 6, lane = t & 63, quad = lane >> 4, lm = lane & 15;
  const int z = blockIdx.z;
  const int bh = blockIdx.y, b = bh >> 1, h = bh & 1;
  const int qbase = blockIdx.x * 256;

  const unsigned short* Qg = QKV + (size_t)(z * 3 + 0) * SZ;
  const unsigned short* Kg = QKV + (size_t)(z * 3 + 1) * SZ;
  const unsigned short* Vg = QKV + (size_t)(z * 3 + 2) * SZ;

  short8 aq[4][2];
#pragma unroll
  for (int qt = 0; qt < 4; ++qt)
#pragma unroll
    for (int c = 0; c < 2; ++c)
      aq[qt][c] = *reinterpret_cast<const short8*>(
          Qg + ((size_t)(b * SS + qbase + qt * 64 + w * 16 + lm)) * DD +
          h * 64 + c * 32 + quad * 8);

  const f32x4 czero = {0.f, 0.f, 0.f, 0.f};
  f32x4 o[4][4];  // [qt][dt]
#pragma unroll
  for (int i = 0; i < 4; ++i)
#pragma unroll
    for (int j = 0; j < 4; ++j) o[i][j] = czero;
  float suml[4][4];  // [qt][r]
#pragma unroll
  for (int i = 0; i < 4; ++i)
#pragma unroll
    for (int j = 0; j < 4; ++j) suml[i][j] = 0.f;

  const int vk = t >> 3, vd0 = (t & 7) * 8;

  for (int kt = 0; kt < 8; ++kt) {
    const int k0 = kt * 64;
    __syncthreads();  // prior Vt fully consumed (bv regs read)
#pragma unroll
    for (int i = 0; i < 2; ++i) {
      const int k = vk + i * 32;
      short8 vv = *reinterpret_cast<const short8*>(
          Vg + ((size_t)(b * SS + k0 + k)) * DD + h * 64 + vd0);
#pragma unroll
      for (int j = 0; j < 8; ++j) {
        const int d = vd0 + j;
        Vt[d * 72 + (k ^ (d & 56))] = (unsigned short)vv[j];
      }
    }
    __syncthreads();

    short8 bk[4][2];
#pragma unroll
    for (int nt = 0; nt < 4; ++nt)
#pragma unroll
      for (int c = 0; c < 2; ++c)
        bk[nt][c] = *reinterpret_cast<const short8*>(
            Kg + ((size_t)(b * SS + k0 + nt * 16 + lm)) * DD + h * 64 +
            c * 32 + quad * 8);
    short8 bvv[4][2];
#pragma unroll
    for (int dt = 0; dt < 4; ++dt) {
      const int d = dt * 16 + lm;
#pragma unroll
      for (int c = 0; c < 2; ++c)
        bvv[dt][c] = *reinterpret_cast<const short8*>(
            &Vt[d * 72 + ((c * 32 + quad * 8) ^ (d & 56))]);
    }

#pragma unroll
    for (int qt = 0; qt < 4; ++qt) {
      f32x4 sacc[4];
#pragma unroll
      for (int nt = 0; nt < 4; ++nt)
        sacc[nt] = __builtin_amdgcn_mfma_f32_16x16x32_bf16(
            aq[qt][0], bk[nt][0], czero, 0, 0, 0);
#pragma unroll
      for (int nt = 0; nt < 4; ++nt)
        sacc[nt] = __builtin_amdgcn_mfma_f32_16x16x32_bf16(
            aq[qt][1], bk[nt][1], sacc[nt], 0, 0, 0);
#pragma unroll
      for (int nt = 0; nt < 4; ++nt) {
#pragma unroll
        for (int r = 0; r < 4; ++r) {
          float p = fexp2_(sacc[nt][r]);
          suml[qt][r] += p;
          Pt[w][(quad * 4 + r) * 72 + nt * 16 + lm] = f2b_trunc(p);
        }
      }
#pragma unroll
      for (int c = 0; c < 2; ++c) {
        short8 ap = *reinterpret_cast<const short8*>(
            &Pt[w][lm * 72 + c * 32 + quad * 8]);
#pragma unroll
        for (int dt = 0; dt < 4; ++dt)
          o[qt][dt] = __builtin_amdgcn_mfma_f32_16x16x32_bf16(
              ap, bvv[dt][c], o[qt][dt], 0, 0, 0);
      }
    }
  }
#pragma unroll
  for (int qt = 0; qt < 4; ++qt)
#pragma unroll
    for (int r = 0; r < 4; ++r) {
#pragma unroll
      for (int m = 1; m < 16; m <<= 1)
        suml[qt][r] += __shfl_xor(suml[qt][r], m);
    }
  const float* vsp = VS + (size_t)(z * BB + b) * DD + h * 64;
#pragma unroll
  for (int qt = 0; qt < 4; ++qt)
#pragma unroll
    for (int dt = 0; dt < 4; ++dt) {
      const int col = dt * 16 + lm;
      const float vs = vsp[col];
#pragma unroll
      for (int r = 0; r < 4; ++r) {
        const int row = qbase + qt * 64 + w * 16 + quad * 4 + r;
        CTX[(size_t)z * SZ + ((size_t)(b * SS + row)) * DD + h * 64 + col] =
            f2b(vs - o[qt][dt][r] * frcp_(suml[qt][r]));
      }
    }
}

// ---------------------------------------------------------------------------
// Fused LN pair, 4 rows/block (1 wave per row).  u32 packed loads/stores.
// ---------------------------------------------------------------------------
__global__ __launch_bounds__(256) void ln_pair(
    const unsigned short* __restrict__ DOUT, const float* __restrict__ lng,
    const float* __restrict__ lnb, unsigned short* __restrict__ GRUIN) {
  const int g = blockIdx.y;
  const int row = blockIdx.x * 4 + (threadIdx.x >> 6);
  const int t = threadIdx.x & 63;
  const int u1t[3] = {1, 2, 0};
  const int u2t[3] = {3, 5, 4};
  float outA = 0.f, outB = 0.f;
#pragma unroll
  for (int half = 0; half < 2; ++half) {
    const int u = half == 0 ? u1t[g] : u2t[g];
    const unsigned short* x = DOUT + (size_t)u * SZ + (size_t)row * DD;
    unsigned int xv = *reinterpret_cast<const unsigned int*>(x + 2 * t);
    float a = b2f((unsigned short)(xv & 0xffffu));
    float c = b2f((unsigned short)(xv >> 16));
    float s = a + c, sq = a * a + c * c;
#pragma unroll
    for (int off = 32; off > 0; off >>= 1) {
      s += __shfl_down(s, off);
      sq += __shfl_down(sq, off);
    }
    s = __shfl(s, 0); sq = __shfl(sq, 0);
    float mean = s * (1.f / 128.f);
    float var = sq * (1.f / 128.f) - mean * mean;
    float rs = rsqrtf(var + 1e-5f);
    const float* gg = lng + u * 128;
    const float* bb = lnb + u * 128;
    outA += (a - mean) * rs * gg[2 * t] + bb[2 * t];
    outB += (c - mean) * rs * gg[2 * t + 1] + bb[2 * t + 1];
  }
  unsigned short* op = GRUIN + (size_t)g * SZ + (size_t)row * DD;
  unsigned int pk = (unsigned int)f2b(0.5f * outA) |
                    ((unsigned int)f2b(0.5f * outB) << 16);
  *reinterpret_cast<unsigned int*>(op + 2 * t) = pk;
}

// ---------------------------------------------------------------------------
// GRU v10 (confirmed best: 173-175us, stable across rounds).  Do not
// restructure (v11 regressed).  grid = (16 bg, 6 rec), block = 512 (8 waves).
// ---------------------------------------------------------------------------
#define AST 136

__global__ __launch_bounds__(512, 1) void gru8(
    const unsigned short* __restrict__ GXR, const unsigned short* __restrict__ WB,
    const float* __restrict__ gbhh, float* __restrict__ HS) {
  __shared__ unsigned short Abuf[2][16 * AST];
  const int rec = blockIdx.y, bg = blockIdx.x;
  const int dir = rec & 1;
  const int t = threadIdx.x;
  const int w = t >> 6, lane = t & 63, q = lane >> 4, lm = lane & 15;
  const int o = w * 16 + lm;
  const int b = bg * 4 + q;

  short8 Bh[3][4];
  const unsigned short* whh = WB + WB_WHH + (size_t)rec * 49152;
#pragma unroll
  for (int gate = 0; gate < 3; ++gate)
#pragma unroll
    for (int c = 0; c < 4; ++c)
      Bh[gate][c] = *reinterpret_cast<const short8*>(
          whh + (size_t)(gate * 128 + o) * 128 + c * 32 + q * 8);
  const float bhn = gbhh[rec * 384 + 256 + o] * (2.f * LOG2E);
  const f32x4 czero = {0.f, 0.f, 0.f, 0.f};
  const f32x4 cbhn = {bhn, 0.f, 0.f, 0.f};

  float h = 0.f, hsum = 0.f;
  for (int i = t; i < 2 * 16 * AST; i += 512)
    (&Abuf[0][0])[i] = 0;

  // gx: 3 ushort loads/step from GXR[rec][b*512 + tt][384] at cols g*128+o.
  const unsigned short* gx0 = GXR + (size_t)rec * 12582912 +
      ((size_t)b * 512 + (dir ? 511 : 0)) * 384 + o;
  const ptrdiff_t st = dir ? -384 : 384;

  unsigned short ring[4][3];
#pragma unroll
  for (int pp = 0; pp < 4; ++pp) {
    const unsigned short* gp = gx0 + (ptrdiff_t)pp * st;
#pragma unroll
    for (int j = 0; j < 3; ++j) ring[pp][j] = gp[j * 128];
  }
  const unsigned short* pf = gx0 + (ptrdiff_t)4 * st;  // prefetch ptr (s+4)
  __syncthreads();

#pragma unroll 4
  for (int s = 0; s < SS; ++s) {
    const int p = s & 1, slot = s & 3;
    const float gxr = b2f(ring[slot][0]);
    const float gxz = b2f(ring[slot][1]);
    const float gxn = b2f(ring[slot][2]);
#pragma unroll
    for (int j = 0; j < 3; ++j) ring[slot][j] = pf[j * 128];
    pf += (s < SS - 5) ? st : 0;  // uniform-cond pointer bump, stays in-bounds

    short8 ah0 = *reinterpret_cast<const short8*>(&Abuf[p][lm * AST + 0 + q * 8]);
    short8 ah1 = *reinterpret_cast<const short8*>(&Abuf[p][lm * AST + 32 + q * 8]);
    short8 ah2 = *reinterpret_cast<const short8*>(&Abuf[p][lm * AST + 64 + q * 8]);
    short8 ah3 = *reinterpret_cast<const short8*>(&Abuf[p][lm * AST + 96 + q * 8]);
    f32x4 r0 = __builtin_amdgcn_mfma_f32_16x16x32_bf16(ah0, Bh[0][0], czero, 0, 0, 0);
    f32x4 r1 = __builtin_amdgcn_mfma_f32_16x16x32_bf16(ah2, Bh[0][2], czero, 0, 0, 0);
    f32x4 z0 = __builtin_amdgcn_mfma_f32_16x16x32_bf16(ah0, Bh[1][0], czero, 0, 0, 0);
    f32x4 z1 = __builtin_amdgcn_mfma_f32_16x16x32_bf16(ah2, Bh[1][2], czero, 0, 0, 0);
    f32x4 n0 = __builtin_amdgcn_mfma_f32_16x16x32_bf16(ah0, Bh[2][0], cbhn, 0, 0, 0);
    f32x4 n1 = __builtin_amdgcn_mfma_f32_16x16x32_bf16(ah2, Bh[2][2], czero, 0, 0, 0);
    r0 = __builtin_amdgcn_mfma_f32_16x16x32_bf16(ah1, Bh[0][1], r0, 0, 0, 0);
    r1 = __builtin_amdgcn_mfma_f32_16x16x32_bf16(ah3, Bh[0][3], r1, 0, 0, 0);
    z0 = __builtin_amdgcn_mfma_f32_16x16x32_bf16(ah1, Bh[1][1], z0, 0, 0, 0);
    z1 = __builtin_amdgcn_mfma_f32_16x16x32_bf16(ah3, Bh[1][3], z1, 0, 0, 0);
    n0 = __builtin_amdgcn_mfma_f32_16x16x32_bf16(ah1, Bh[2][1], n0, 0, 0, 0);
    n1 = __builtin_amdgcn_mfma_f32_16x16x32_bf16(ah3, Bh[2][3], n1, 0, 0, 0);

    float rr = frcp_(1.f + fexp2_(-(gxr + r0[0] + r1[0])));
    float zz = frcp_(1.f + fexp2_(-(gxz + z0[0] + z1[0])));
    float nn = 1.f - 2.f * frcp_(fexp2_(gxn + rr * (n0[0] + n1[0])) + 1.f);
    h = nn + zz * (h - nn);
    hsum += h;
    Abuf[p ^ 1][(q * 4) * AST + o] = f2b_trunc(h);
    asm volatile("s_waitcnt lgkmcnt(0)\n\ts_barrier" ::: "memory");
  }
  HS[((size_t)rec * BB + bg * 4 + q) * 128 + o] = hsum;
}

// ---------------------------------------------------------------------------
// Head: pooled -> Linear -> BN(eval) -> ReLU6 -> Linear.  grid=64, block=256.
// ---------------------------------------------------------------------------
__global__ __launch_bounds__(256) void head_kernel(
    const float* __restrict__ HS, const float* __restrict__ fW1,
    const float* __restrict__ fb1, const float* __restrict__ bng,
    const float* __restrict__ bnb, const float* __restrict__ fW2,
    const float* __restrict__ fb2, float* __restrict__ out) {
  __shared__ float pl[384];
  __shared__ float h1[256];
  int b = blockIdx.x, n = threadIdx.x;
  {
    int j = n;
    int seg = j >> 7, oo = j & 127;
    pl[j] = (HS[((size_t)seg * BB + b) * 128 + oo] +
             HS[((size_t)(seg + 3) * BB + b) * 128 + oo]) * (0.5f / 512.f);
  }
  if (n < 128) {
    int j = 256 + n;
    int seg = j >> 7, oo = j & 127;
    pl[j] = (HS[((size_t)seg * BB + b) * 128 + oo] +
             HS[((size_t)(seg + 3) * BB + b) * 128 + oo]) * (0.5f / 512.f);
  }
  __syncthreads();
  float acc = fb1[n];
  for (int k = 0; k < 384; ++k) acc += pl[k] * fW1[k * 256 + n];
  float hv = acc * rsqrtf(1.f + 1e-5f) * bng[n] + bnb[n];
  hv = fminf(fmaxf(hv, 0.f), 6.f);
  h1[n] = hv;
  __syncthreads();
  if (n < 8) {
    float a2 = fb2[n];
    for (int k = 0; k < 256; ++k) a2 += h1[k] * fW2[k * 8 + n];
    out[b * 8 + n] = a2;
  }
}

// ---------------------------------------------------------------------------
extern "C" void kernel_launch(void* const* d_in, const int* in_sizes, int n_in,
                              void* d_out, int out_size, void* d_ws,
                              size_t ws_size, hipStream_t stream) {
  (void)in_sizes; (void)n_in; (void)out_size; (void)ws_size;
  const float* text = (const float*)d_in[0];
  const float* vis  = (const float*)d_in[1];
  const float* aud  = (const float*)d_in[2];
  const float* fc1W = (const float*)d_in[3];
  const float* fc1b = (const float*)d_in[4];
  const float* fc2W = (const float*)d_in[5];
  const float* fc2b = (const float*)d_in[6];
  const float* fc3W = (const float*)d_in[7];
  const float* fc3b = (const float*)d_in[8];
  const float* Wq = (const float*)d_in[9];
  const float* bq = (const float*)d_in[10];
  const float* Wk = (const float*)d_in[11];
  const float* bk = (const float*)d_in[12];
  const float* Wv = (const float*)d_in[13];
  const float* bv = (const float*)d_in[14];
  const float* Wd = (const float*)d_in[15];
  const float* bd = (const float*)d_in[16];
  const float* lng = (const float*)d_in[17];
  const float* lnb = (const float*)d_in[18];
  const float* gWih = (const float*)d_in[19];
  const float* gWhh = (const float*)d_in[20];
  const float* gbih = (const float*)d_in[21];
  const float* gbhh = (const float*)d_in[22];
  const float* fW1 = (const float*)d_in[23];
  const float* fb1 = (const float*)d_in[24];
  const float* bng = (const float*)d_in[25];
  const float* bnb = (const float*)d_in[26];
  const float* fW2 = (const float*)d_in[27];
  const float* fb2 = (const float*)d_in[28];
  float* out = (float*)d_out;

  unsigned short* WSB = (unsigned short*)d_ws;
  unsigned short* T   = WSB;
  unsigned short* Vv  = WSB + SZ;
  unsigned short* Aa  = WSB + 2 * SZ;
  unsigned short* QKV = WSB + 3 * SZ;
  unsigned short* CTX = WSB + 12 * SZ;
  unsigned short* DOUT = WSB;
  unsigned short* GXR = WSB;              // slices 0..17 ([6][32768][384])
  unsigned short* GRUIN = WSB + 18 * SZ;  // slices 18..20
  unsigned short* WB  = WSB + 21 * SZ;
  float* VS = (float*)(WSB + 21 * SZ + 1048576);
  float* HS = VS + 6 * 64 * 128;
  float* gbihs = HS + 6 * 64 * 128;       // 2304 floats
  float* bqs = gbihs + 6 * 384;           // 768 floats

  prep_kernel<<<dim3(1024), dim3(256), 0, stream>>>(
      fc1W, fc2W, fc3W, Wq, Wk, Wv, Wd, gWih, gWhh, gbih, gbhh, bq, WB,
      gbihs, bqs);
  hipMemsetAsync(VS, 0, 6 * 64 * 128 * sizeof(float), stream);

  {
    GArgs ga{};
    ga.gw = 1;
    ga.g[0] = {text, WB + WB_P1, fc1b, T, 300, 320, 1, 1, 128};  // abf=1: aligned
    ga.g[1] = {vis,  WB + WB_P2, fc2b, Vv, 35, 64, 0, 1, 128};
    ga.g[2] = {aud,  WB + WB_P3, fc3b, Aa, 74, 96, 0, 1, 128};
    gemm_proj<<<dim3(256, 1, 3), dim3(256), 0, stream>>>(ga);
  }

  const int qsel[6] = {0, 2, 0, 1, 1, 2};
  const int ksel[6] = {2, 0, 1, 0, 2, 1};
  unsigned short* proj[3] = {T, Vv, Aa};

  for (int phase = 0; phase < 2; ++phase) {
    // Grouped QKV: 3 A-groups (one per proj source), 2-4 W-tiles each.
    GArgs ga{};
    ga.gw = 4;
    int cnt[3] = {0, 0, 0};
    for (int ul = 0; ul < 3; ++ul) {
      int u = phase * 3 + ul;
      for (int op = 0; op < 3; ++op) {
        int a = (op == 0) ? qsel[u] : ksel[u];
        int z = ul * 3 + op;
        const float* bias = (op == 0) ? (bqs + u * 128)
                          : (op == 1) ? (bk + u * 128) : (bv + u * 128);
        float* vsum = (op == 2) ? (VS + (size_t)u * BB * DD) : nullptr;
        ga.g[a * 4 + cnt[a]] = {proj[a],
                                WB + WB_QKVD + op * 98304 + u * 16384, bias,
                                QKV + (size_t)z * SZ, 128, 128, 0, 1, 128,
                                vsum};
        cnt[a]++;
      }
    }
    for (int a = 0; a < 3; ++a) ga.g[a * 4].abf = cnt[a];
    gemm_k128g<<<dim3(256, 1, 3), dim3(256), 0, stream>>>(ga);
    attn2<<<dim3(2, 128, 3), dim3(256), 0, stream>>>(
        QKV, VS + phase * 3 * BB * DD, CTX + (size_t)phase * 3 * SZ);
  }

  {
    // Dense: no A sharing -> 6 singleton groups (gw=1, nw=1 == round-4 path).
    GArgs ga{};
    ga.gw = 1;
    for (int u = 0; u < 6; ++u)
      ga.g[u] = {CTX + (size_t)u * SZ, WB + WB_QKVD + 3 * 98304 + u * 16384,
                 bd + u * 128, DOUT + (size_t)u * SZ, 128, 128, 1, 1, 128};
    gemm_k128g<<<dim3(256, 1, 6), dim3(256), 0, stream>>>(ga);
  }

  ln_pair<<<dim3(NROW / 4, 3), dim3(256), 0, stream>>>(DOUT, lng, lnb, GRUIN);

  // gx = GRUIN[g] @ Wih[rec]^T + gbihs[rec] -> row-major GXR (coalesced).
  // Grouped: 3 A-groups (one per GRUIN slice) x 6 W-tiles (2 rec x 3 ny).
  {
    GArgs ga{};
    ga.gw = 6;
    for (int g = 0; g < 3; ++g) {
      for (int i = 0; i < 6; ++i) {
        int dr = i / 3, ny = i % 3, r6 = g * 2 + dr;
        ga.g[g * 6 + i] = {GRUIN + (size_t)g * SZ,
                           WB + WB_WIH + r6 * 49152 + ny * 16384,
                           gbihs + r6 * 384 + ny * 128,
                           GXR + (size_t)r6 * 12582912 + ny * 128,
                           128, 128, (i == 0) ? 6 : 0, 1, 384, nullptr};
      }
    }
    gemm_k128g<<<dim3(256, 1, 3), dim3(256), 0, stream>>>(ga);
  }

  gru8<<<dim3(16, 6), dim3(512), 0, stream>>>(GXR, WB, gbhh, HS);
  head_kernel<<<dim3(BB), dim3(256), 0, stream>>>(HS, fW1, fb1, bng, bnb, fW2, fb2, out);
}